// Round 5
// baseline (8438.549 us; speedup 1.0000x reference)
//
#include <hip/hip_runtime.h>
#include <stdint.h>

// SpikingQNetwork B=16384 D=512 H=2048 H2=1024 A=8 T=8.
// Fast path: bf16 2-term-split MFMA GEMMs (deviation ~1e-5 at mem level).
// Reference mimicry: np reference = float32 numpy (BLAS sgemm = sequential
// ascending-k FMA chain per element). Any neuron whose fast membrane comes
// within MARGIN of threshold is recomputed with an exact f32 sequential-FMA
// chain (+ RN-exact recurrence) and its spike bits patched via atomicXor.
// Unflagged decisions provably match np (deviation << MARGIN).
// Output layer: f64 from spike bits (no thresholds downstream).

typedef __bf16 bf16;
typedef __attribute__((ext_vector_type(8))) __bf16 bf16x8;
typedef __attribute__((ext_vector_type(4))) float f32x4;

#define CAP1 2097152
#define CAP2 2097152
#define MARGIN 2e-3f

__device__ __forceinline__ void gl16(const void* g, void* l) {
  __builtin_amdgcn_global_load_lds(
      (const __attribute__((address_space(1))) uint32_t*)g,
      (__attribute__((address_space(3))) uint32_t*)l, 16, 0, 0);
}

__device__ __forceinline__ float clampf(float v) {
  return fminf(fmaxf(v, 0.f), 1.f);
}

__device__ __forceinline__ uint32_t expand2(uint32_t b) {
  // 2 spike bits -> 2 packed bf16 (1.0 = 0x3F80)
  return ((b & 1u) ? 0x3F80u : 0u) | ((b & 2u) ? 0x3F800000u : 0u);
}

// ---------------- splits (bf16 hi/lo) -------------------------------------

__global__ void split_x_kernel(const float* __restrict__ x, bf16* __restrict__ Ax) {
  int i = blockIdx.x * 256 + threadIdx.x;   // B*D
  int b = i >> 9, d = i & 511;
  float v = x[i];
  bf16 hi = (bf16)v;
  bf16 lo = (bf16)(v - (float)hi);
  size_t base = (size_t)b * 1024;
  Ax[base + d] = hi;
  Ax[base + 512 + d] = lo;
}

__global__ void split_w1_kernel(const float* __restrict__ W1, bf16* __restrict__ B0,
                                bf16* __restrict__ B1) {
  int i = blockIdx.x * 256 + threadIdx.x;   // H*D
  int r = i >> 9, d = i & 511;
  float v = W1[i];
  bf16 hi = (bf16)v;
  bf16 lo = (bf16)(v - (float)hi);
  size_t base = (size_t)r * 1024;
  B0[base + d] = hi;  B0[base + 512 + d] = lo;   // [w0|w1]
  B1[base + d] = lo;  B1[base + 512 + d] = hi;   // [w1|w0]
}

__global__ void split_w2_kernel(const float* __restrict__ W2, bf16* __restrict__ Wh,
                                bf16* __restrict__ Wl) {
  int i = blockIdx.x * 256 + threadIdx.x;   // H2*H
  float v = W2[i];
  bf16 hi = (bf16)v;
  Wh[i] = hi;
  Wl[i] = (bf16)(v - (float)hi);
}

// -------- GEMM1 + fused LIF1: spike bits + near-threshold flags -----------

#define SA_OFF  0
#define SB0_OFF 16384
#define SB1_OFF 32768

__global__ __launch_bounds__(256, 2) void gemm1_lif1_kernel(
    const bf16* __restrict__ A, const bf16* __restrict__ B0,
    const bf16* __restrict__ B1, const float* __restrict__ bias,
    const float* __restrict__ beta1p,
    uint32_t* __restrict__ spkbits1, uint2* __restrict__ flag1,
    uint32_t* __restrict__ cnt1)
{
  __shared__ __align__(16) uint8_t lds[49152];
  const int tid = threadIdx.x;
  const int lane = tid & 63;
  const int wave = tid >> 6;
  const int wm = (wave >> 1) * 64, wn = (wave & 1) * 64;
  const size_t brow = (size_t)blockIdx.x * 128;
  const size_t bcol = (size_t)blockIdx.y * 128;
  const int K = 1024;
  const float be = clampf(beta1p[0]);

  const bf16* gA  = A  + brow * K;
  const bf16* gB0 = B0 + bcol * K;
  const bf16* gB1 = B1 + bcol * K;

  f32x4 acc[4][4] = {};

  for (int kk = 0; kk < K; kk += 64) {
#pragma unroll
    for (int q = 0; q < 4; ++q) {
      const int flat = q * 256 + tid;
      const int row = flat >> 3;
      const int c8 = (flat & 7) * 8;
      gl16(gA  + (size_t)row * K + kk + c8, lds + SA_OFF  + flat * 16);
      gl16(gB0 + (size_t)row * K + kk + c8, lds + SB0_OFF + flat * 16);
      gl16(gB1 + (size_t)row * K + kk + c8, lds + SB1_OFF + flat * 16);
    }
    asm volatile("s_waitcnt vmcnt(0)" ::: "memory");
    __syncthreads();
#pragma unroll
    for (int ks = 0; ks < 2; ++ks) {
      const int koff = (ks * 32 + (lane >> 4) * 8) * 2;  // bytes
      bf16x8 af[4], b0f[4], b1f[4];
#pragma unroll
      for (int i = 0; i < 4; ++i) {
        af[i]  = *(const bf16x8*)(lds + SA_OFF  + (wm + i * 16 + (lane & 15)) * 128 + koff);
        b0f[i] = *(const bf16x8*)(lds + SB0_OFF + (wn + i * 16 + (lane & 15)) * 128 + koff);
        b1f[i] = *(const bf16x8*)(lds + SB1_OFF + (wn + i * 16 + (lane & 15)) * 128 + koff);
      }
#pragma unroll
      for (int m = 0; m < 4; ++m)
#pragma unroll
        for (int n = 0; n < 4; ++n) {
          acc[m][n] = __builtin_amdgcn_mfma_f32_16x16x32_bf16(af[m], b0f[n], acc[m][n], 0, 0, 0);
          acc[m][n] = __builtin_amdgcn_mfma_f32_16x16x32_bf16(af[m], b1f[n], acc[m][n], 0, 0, 0);
        }
    }
    __syncthreads();
  }

  // fold bias into acc (acc becomes cur1, constant over t)
#pragma unroll
  for (int n = 0; n < 4; ++n) {
    const float bv = bias[bcol + wn + n * 16 + (lane & 15)];
#pragma unroll
    for (int m = 0; m < 4; ++m)
#pragma unroll
      for (int j = 0; j < 4; ++j) acc[m][n][j] += bv;
  }

  float mem64[4][4][4];
  uint32_t hist64[4][4][4];
#pragma unroll
  for (int m = 0; m < 4; ++m)
#pragma unroll
    for (int n = 0; n < 4; ++n)
#pragma unroll
      for (int j = 0; j < 4; ++j) { mem64[m][n][j] = 0.f; hist64[m][n][j] = 0u; }
  unsigned long long flg = 0;

  for (int t = 0; t < 8; ++t) {
#pragma unroll
    for (int m = 0; m < 4; ++m)
#pragma unroll
      for (int n = 0; n < 4; ++n)
#pragma unroll
        for (int j = 0; j < 4; ++j) {
          float mv = mem64[m][n][j];
          float rst = (mv > 1.f) ? 1.f : 0.f;
          mv = be * mv + acc[m][n][j] - rst;
          mem64[m][n][j] = mv;
          uint32_t bit = (mv > 1.f) ? 1u : 0u;
          hist64[m][n][j] |= bit << t;
          if (fabsf(mv - 1.f) < MARGIN) flg |= 1ull << (m * 16 + n * 4 + j);
          const int row = wm + m * 16 + (lane >> 4) * 4 + j;
          const int col = wn + n * 16 + (lane & 15);
          lds[row * 128 + col] = (uint8_t)bit;
        }
    __syncthreads();
#pragma unroll
    for (int q = 0; q < 2; ++q) {
      const int w = q * 256 + tid;
      const int r = w >> 2, c = w & 3;
      uint32_t word = 0;
#pragma unroll
      for (int g = 0; g < 8; ++g) {
        uint32_t u = *(const uint32_t*)(lds + r * 128 + c * 32 + g * 4);
        uint32_t nib = ((u & 0x01010101u) * 0x01020408u) >> 24;
        word |= (nib & 0xFu) << (g * 4);
      }
      spkbits1[((size_t)t * 64 + (bcol >> 5) + c) * 16384 + brow + r] = word;
    }
    __syncthreads();
  }

  if (flg) {
#pragma unroll
    for (int m = 0; m < 4; ++m)
#pragma unroll
      for (int n = 0; n < 4; ++n)
#pragma unroll
        for (int j = 0; j < 4; ++j)
          if ((flg >> (m * 16 + n * 4 + j)) & 1ull) {
            const uint32_t h = (uint32_t)(bcol + wn + n * 16 + (lane & 15));
            const uint32_t b = (uint32_t)(brow + wm + m * 16 + (lane >> 4) * 4 + j);
            uint32_t pos = atomicAdd(cnt1, 1u);
            if (pos < CAP1) {
              uint2 en; en.x = (h << 14) | b; en.y = hist64[m][n][j];
              flag1[pos] = en;
            }
          }
  }
}

// ------- repair1: f32 sequential-FMA (BLAS-order mimicry) redo -------------

__global__ __launch_bounds__(256) void repair1_kernel(
    const float* __restrict__ x, const float* __restrict__ W1,
    const float* __restrict__ b1, const float* __restrict__ beta1p,
    const uint2* __restrict__ flag1, const uint32_t* __restrict__ cnt1,
    uint32_t* __restrict__ spkbits1)
{
  uint32_t n = cnt1[0]; if (n > CAP1) n = CAP1;
  const float be = clampf(beta1p[0]);
  for (uint32_t i = blockIdx.x * 256 + threadIdx.x; i < n; i += gridDim.x * 256) {
    uint2 e = flag1[i];
    int h = e.x >> 14, b = e.x & 16383;
    const float* xr = x + (size_t)b * 512;
    const float* wr = W1 + (size_t)h * 512;
    float s = 0.f;                       // sgemm: sequential ascending-k FMA
    for (int d = 0; d < 512; ++d) s = fmaf(xr[d], wr[d], s);
    s = __fadd_rn(s, b1[h]);             // + b1 (separate np op)
    float m = 0.f; uint32_t eb = 0;
#pragma unroll
    for (int t = 0; t < 8; ++t) {
      float rst = (__fsub_rn(m, 1.f) > 0.f) ? 1.f : 0.f;
      m = __fsub_rn(__fadd_rn(__fmul_rn(be, m), s), rst);
      if (__fsub_rn(m, 1.f) > 0.f) eb |= 1u << t;
    }
    uint32_t diff = eb ^ (e.y & 0xFFu);
    if (diff) {
#pragma unroll
      for (int t = 0; t < 8; ++t)
        if ((diff >> t) & 1u)
          atomicXor(&spkbits1[((size_t)t * 64 + (h >> 5)) * 16384 + b], 1u << (h & 31));
    }
  }
}

// ---------------- step2: fused per-t GEMM + LIF2 -> spike bits + flags -----

__global__ __launch_bounds__(256, 2) void step2_kernel(
    const uint32_t* __restrict__ spkbits1,
    const bf16* __restrict__ W2h, const bf16* __restrict__ W2l,
    const float* __restrict__ b2, const float* __restrict__ beta2p,
    uint32_t* __restrict__ spkbits2, uint32_t* __restrict__ flag2,
    uint32_t* __restrict__ cnt2)
{
  __shared__ __align__(16) uint8_t lds[49152];
  const int K = 2048;
  const int tid = threadIdx.x;
  const int lane = tid & 63;
  const int wave = tid >> 6;
  const int wm = (wave >> 1) * 64, wn = (wave & 1) * 64;
  const size_t brow = (size_t)blockIdx.x * 128;
  const size_t bcol = (size_t)blockIdx.y * 128;
  const float be2 = clampf(beta2p[0]);

  const bf16* gB0 = W2h + bcol * K;
  const bf16* gB1 = W2l + bcol * K;

  float b2c[4];
#pragma unroll
  for (int n = 0; n < 4; ++n) b2c[n] = b2[bcol + wn + n * 16 + (lane & 15)];

  const int ar = tid & 127;
  const int aw = tid >> 7;

  f32x4 acc[4][4] = {};       // mem2, persistent across t
  unsigned long long flg = 0;

  for (int t = 0; t < 8; ++t) {
#pragma unroll
    for (int m = 0; m < 4; ++m)
#pragma unroll
      for (int n = 0; n < 4; ++n)
#pragma unroll
        for (int j = 0; j < 4; ++j) {
          float v = acc[m][n][j];
          float rst = (v > 1.f) ? 1.f : 0.f;
          acc[m][n][j] = be2 * v + (b2c[n] - rst);
        }

    for (int kk = 0; kk < K; kk += 64) {
      uint32_t bits = spkbits1[((size_t)t * 64 + (kk >> 5) + aw) * 16384 + brow + ar];
#pragma unroll
      for (int c = 0; c < 4; ++c) {
        uint4 u;
        u.x = expand2(bits >> (8 * c));
        u.y = expand2(bits >> (8 * c + 2));
        u.z = expand2(bits >> (8 * c + 4));
        u.w = expand2(bits >> (8 * c + 6));
        const int slot = (aw * 4 + c) ^ (ar & 7);
        *(uint4*)(lds + SA_OFF + ar * 128 + slot * 16) = u;
      }
#pragma unroll
      for (int q = 0; q < 4; ++q) {
        const int flat = q * 256 + tid;
        const int row = flat >> 3;
        const int c8 = (flat & 7) * 8;
        gl16(gB0 + (size_t)row * K + kk + c8, lds + SB0_OFF + flat * 16);
        gl16(gB1 + (size_t)row * K + kk + c8, lds + SB1_OFF + flat * 16);
      }
      asm volatile("s_waitcnt vmcnt(0)" ::: "memory");
      __syncthreads();
#pragma unroll
      for (int ks = 0; ks < 2; ++ks) {
        bf16x8 af[4], b0f[4], b1f[4];
#pragma unroll
        for (int i = 0; i < 4; ++i) {
          const int ra = wm + i * 16 + (lane & 15);
          const int slot = (ks * 4 + (lane >> 4)) ^ (ra & 7);
          af[i] = *(const bf16x8*)(lds + SA_OFF + ra * 128 + slot * 16);
          const int rb = wn + i * 16 + (lane & 15);
          const int koff = (ks * 32 + (lane >> 4) * 8) * 2;
          b0f[i] = *(const bf16x8*)(lds + SB0_OFF + rb * 128 + koff);
          b1f[i] = *(const bf16x8*)(lds + SB1_OFF + rb * 128 + koff);
        }
#pragma unroll
        for (int m = 0; m < 4; ++m)
#pragma unroll
          for (int n = 0; n < 4; ++n) {
            acc[m][n] = __builtin_amdgcn_mfma_f32_16x16x32_bf16(af[m], b0f[n], acc[m][n], 0, 0, 0);
            acc[m][n] = __builtin_amdgcn_mfma_f32_16x16x32_bf16(af[m], b1f[n], acc[m][n], 0, 0, 0);
          }
      }
      __syncthreads();
    }

#pragma unroll
    for (int m = 0; m < 4; ++m)
#pragma unroll
      for (int n = 0; n < 4; ++n)
#pragma unroll
        for (int j = 0; j < 4; ++j) {
          const int row = wm + m * 16 + (lane >> 4) * 4 + j;
          const int col = wn + n * 16 + (lane & 15);
          float v = acc[m][n][j];
          lds[row * 128 + col] = (v > 1.f) ? 1 : 0;
          if (fabsf(v - 1.f) < MARGIN) flg |= 1ull << (m * 16 + n * 4 + j);
        }
    __syncthreads();
#pragma unroll
    for (int q = 0; q < 2; ++q) {
      const int w = q * 256 + tid;
      const int r = w >> 2, c = w & 3;
      uint32_t word = 0;
#pragma unroll
      for (int g = 0; g < 8; ++g) {
        uint32_t u = *(const uint32_t*)(lds + r * 128 + c * 32 + g * 4);
        uint32_t nib = ((u & 0x01010101u) * 0x01020408u) >> 24;
        word |= (nib & 0xFu) << (g * 4);
      }
      spkbits2[((size_t)t * 32 + (bcol >> 5) + c) * 16384 + brow + r] = word;
    }
    __syncthreads();
  }

  if (flg) {
#pragma unroll
    for (int m = 0; m < 4; ++m)
#pragma unroll
      for (int n = 0; n < 4; ++n)
#pragma unroll
        for (int j = 0; j < 4; ++j)
          if ((flg >> (m * 16 + n * 4 + j)) & 1ull) {
            const int row = wm + m * 16 + (lane >> 4) * 4 + j;
            const int col = wn + n * 16 + (lane & 15);
            uint32_t pos = atomicAdd(cnt2, 1u);
            if (pos < CAP2)
              flag2[pos] = (uint32_t)(((brow + row) << 10) | (bcol + col));
          }
  }
}

// ------- repair2: f32 sequential-FMA (BLAS-order mimicry) redo -------------

__global__ __launch_bounds__(256) void repair2_kernel(
    const uint32_t* __restrict__ spkbits1, const float* __restrict__ W2,
    const float* __restrict__ b2, const float* __restrict__ beta2p,
    const uint32_t* __restrict__ flag2, const uint32_t* __restrict__ cnt2,
    uint32_t* __restrict__ spkbits2)
{
  uint32_t n = cnt2[0]; if (n > CAP2) n = CAP2;
  const float be = clampf(beta2p[0]);
  for (uint32_t i = blockIdx.x * 256 + threadIdx.x; i < n; i += gridDim.x * 256) {
    uint32_t e = flag2[i];
    int b = e >> 10, h2 = e & 1023;
    const float* wr = W2 + (size_t)h2 * 2048;
    const float bias = b2[h2];
    float m = 0.f;
    for (int t = 0; t < 8; ++t) {
      float s = 0.f;   // fma(spk,w,c): spk=1 -> RN(w+c); spk=0 -> c (exact skip)
      for (int w = 0; w < 64; ++w) {
        uint32_t bits = spkbits1[((size_t)t * 64 + w) * 16384 + b];
        while (bits) {                       // ascending k within word (ctz)
          int k = __builtin_ctz(bits);
          bits &= bits - 1;
          s = __fadd_rn(s, wr[w * 32 + k]);
        }
      }
      s = __fadd_rn(s, bias);
      float rst = (__fsub_rn(m, 1.f) > 0.f) ? 1.f : 0.f;
      m = __fsub_rn(__fadd_rn(__fmul_rn(be, m), s), rst);
      uint32_t exact = (__fsub_rn(m, 1.f) > 0.f) ? 1u : 0u;
      uint32_t* wp = &spkbits2[((size_t)t * 32 + (h2 >> 5)) * 16384 + b];
      uint32_t stored = (*wp >> (h2 & 31)) & 1u;
      if (stored != exact) atomicXor(wp, 1u << (h2 & 31));
    }
  }
}

// ---------------- output: f64 mem_out recurrence + max from spike bits -----

__global__ __launch_bounds__(256) void out_kernel(
    const uint32_t* __restrict__ spkbits2, const float* __restrict__ Wo,
    const float* __restrict__ bo, const float* __restrict__ betaop,
    float* __restrict__ out)
{
  const int wave = threadIdx.x >> 6, lane = threadIdx.x & 63;
  const int b = blockIdx.x * 4 + wave;
  const double beo = (double)clampf(betaop[0]);
  const int wrd = lane >> 1;
  const int half = lane & 1;
  const int h2base = lane * 16;
  double mo[8] = {0, 0, 0, 0, 0, 0, 0, 0};
  double mx[8];
#pragma unroll
  for (int a = 0; a < 8; ++a) mx[a] = -1e9;
  for (int t = 0; t < 8; ++t) {
    uint32_t word = spkbits2[((size_t)t * 32 + wrd) * 16384 + b];
    uint32_t bits = (word >> (half * 16)) & 0xFFFFu;
    double s[8] = {0, 0, 0, 0, 0, 0, 0, 0};
#pragma unroll
    for (int k = 0; k < 16; ++k) {
      if ((bits >> k) & 1u) {
#pragma unroll
        for (int a = 0; a < 8; ++a)
          s[a] += (double)Wo[a * 1024 + h2base + k];
      }
    }
#pragma unroll
    for (int a = 0; a < 8; ++a)
#pragma unroll
      for (int off = 32; off > 0; off >>= 1)
        s[a] += __shfl_down(s[a], off, 64);
    if (lane == 0) {
#pragma unroll
      for (int a = 0; a < 8; ++a) {
        mo[a] = beo * mo[a] + (s[a] + (double)bo[a]);
        mx[a] = fmax(mx[a], mo[a]);
      }
    }
  }
  if (lane == 0) {
#pragma unroll
    for (int a = 0; a < 8; ++a)
      out[(size_t)b * 8 + a] = (float)mx[a];
  }
}

__global__ void zero_hdr_kernel(uint32_t* p) {
  if (threadIdx.x < 64) p[threadIdx.x] = 0;
}

__global__ void fill_sentinel(float* out, int n, float v) {
  int i = blockIdx.x * 256 + threadIdx.x;
  if (i < n) out[i] = v;
}

// ---------------- launch ----------------

extern "C" void kernel_launch(void* const* d_in, const int* in_sizes, int n_in,
                              void* d_out, int out_size, void* d_ws, size_t ws_size,
                              hipStream_t stream)
{
  (void)in_sizes; (void)n_in;
  const float* x   = (const float*)d_in[0];
  const float* W1  = (const float*)d_in[1];
  const float* b1  = (const float*)d_in[2];
  const float* W2  = (const float*)d_in[3];
  const float* b2  = (const float*)d_in[4];
  const float* Wo  = (const float*)d_in[5];
  const float* bo  = (const float*)d_in[6];
  const float* be1 = (const float*)d_in[7];
  const float* be2 = (const float*)d_in[8];
  const float* beo = (const float*)d_in[9];
  float* out = (float*)d_out;

  const int B = 16384, D = 512, H = 2048, H2 = 1024;

  const size_t sz_hdr  = 256;
  const size_t sz_Ax   = (size_t)B * 1024 * 2;        // 32 MB
  const size_t sz_W1s  = (size_t)H * 1024 * 2;        // 4 MB each
  const size_t sz_W2s  = (size_t)H2 * H * 2;          // 4 MB each
  const size_t sz_b1   = (size_t)8 * 64 * B * 4;      // 32 MB
  const size_t sz_b2   = (size_t)8 * 32 * B * 4;      // 16 MB
  const size_t sz_f1   = (size_t)CAP1 * 8;            // 16 MB
  const size_t sz_f2   = (size_t)CAP2 * 4;            // 8 MB
  const size_t need = sz_hdr + sz_Ax + 2 * sz_W1s + 2 * sz_W2s +
                      sz_b1 + sz_b2 + sz_f1 + sz_f2;  // ~120 MB

  if (ws_size < need) {  // encode ws_size (MB) in the sentinel
    fill_sentinel<<<(out_size + 255) / 256, 256, 0, stream>>>(
        out, out_size, 1000.0f + (float)(ws_size >> 20));
    return;
  }

  uint8_t* p = (uint8_t*)d_ws;
  uint32_t* hdr = (uint32_t*)p;     p += sz_hdr;
  bf16* Ax      = (bf16*)p;         p += sz_Ax;
  bf16* W1B0    = (bf16*)p;         p += sz_W1s;
  bf16* W1B1    = (bf16*)p;         p += sz_W1s;
  bf16* W2h     = (bf16*)p;         p += sz_W2s;
  bf16* W2l     = (bf16*)p;         p += sz_W2s;
  uint32_t* spkbits1 = (uint32_t*)p; p += sz_b1;
  uint32_t* spkbits2 = (uint32_t*)p; p += sz_b2;
  uint2* flag1  = (uint2*)p;        p += sz_f1;
  uint32_t* flag2 = (uint32_t*)p;   p += sz_f2;
  uint32_t* cnt1 = hdr + 0;
  uint32_t* cnt2 = hdr + 1;

  zero_hdr_kernel<<<1, 64, 0, stream>>>(hdr);
  split_x_kernel <<<(B * D) / 256, 256, 0, stream>>>(x, Ax);
  split_w1_kernel<<<(H * D) / 256, 256, 0, stream>>>(W1, W1B0, W1B1);
  split_w2_kernel<<<(H2 * H) / 256, 256, 0, stream>>>(W2, W2h, W2l);

  gemm1_lif1_kernel<<<dim3(B / 128, H / 128), 256, 0, stream>>>(
      Ax, W1B0, W1B1, b1, be1, spkbits1, flag1, cnt1);
  repair1_kernel<<<256, 256, 0, stream>>>(x, W1, b1, be1, flag1, cnt1, spkbits1);

  step2_kernel<<<dim3(B / 128, H2 / 128), 256, 0, stream>>>(
      spkbits1, W2h, W2l, b2, be2, spkbits2, flag2, cnt2);
  repair2_kernel<<<256, 256, 0, stream>>>(spkbits1, W2, b2, be2, flag2, cnt2, spkbits2);

  out_kernel<<<B / 4, 256, 0, stream>>>(spkbits2, Wo, bo, beo, out);
}

// Round 6
// 8336.199 us; speedup vs baseline: 1.0123x; 1.0123x over previous
//
#include <hip/hip_runtime.h>
#include <stdint.h>

// SpikingQNetwork B=16384 D=512 H=2048 H2=1024 A=8 T=8.
// Fast path: bf16 2-term-split MFMA GEMMs; near-threshold neurons repaired
// with f32 sequential-FMA (BLAS mimicry); spike bits patched via atomicXor.
// R5->R6: (1) LIF1 epilogue loop-inverted + ballot-packed (no scratch spill,
// no LDS plane, no extra barriers); (2) LDS tiles XOR-swizzled via
// pre-swizzled gl16 source + swizzled fragment reads (bank-conflict fix);
// (3) step2 per-t epilogue ballot-packed (removes 2 barriers/t).

typedef __bf16 bf16;
typedef __attribute__((ext_vector_type(8))) __bf16 bf16x8;
typedef __attribute__((ext_vector_type(4))) float f32x4;

#define CAP1 2097152
#define CAP2 2097152
#define MARGIN 2e-3f

__device__ __forceinline__ void gl16(const void* g, void* l) {
  __builtin_amdgcn_global_load_lds(
      (const __attribute__((address_space(1))) uint32_t*)g,
      (__attribute__((address_space(3))) uint32_t*)l, 16, 0, 0);
}

__device__ __forceinline__ float clampf(float v) {
  return fminf(fmaxf(v, 0.f), 1.f);
}

__device__ __forceinline__ uint32_t expand2(uint32_t b) {
  // 2 spike bits -> 2 packed bf16 (1.0 = 0x3F80)
  return ((b & 1u) ? 0x3F80u : 0u) | ((b & 2u) ? 0x3F800000u : 0u);
}

// ---------------- splits (bf16 hi/lo) -------------------------------------

__global__ void split_x_kernel(const float* __restrict__ x, bf16* __restrict__ Ax) {
  int i = blockIdx.x * 256 + threadIdx.x;   // B*D
  int b = i >> 9, d = i & 511;
  float v = x[i];
  bf16 hi = (bf16)v;
  bf16 lo = (bf16)(v - (float)hi);
  size_t base = (size_t)b * 1024;
  Ax[base + d] = hi;
  Ax[base + 512 + d] = lo;
}

__global__ void split_w1_kernel(const float* __restrict__ W1, bf16* __restrict__ B0,
                                bf16* __restrict__ B1) {
  int i = blockIdx.x * 256 + threadIdx.x;   // H*D
  int r = i >> 9, d = i & 511;
  float v = W1[i];
  bf16 hi = (bf16)v;
  bf16 lo = (bf16)(v - (float)hi);
  size_t base = (size_t)r * 1024;
  B0[base + d] = hi;  B0[base + 512 + d] = lo;   // [w0|w1]
  B1[base + d] = lo;  B1[base + 512 + d] = hi;   // [w1|w0]
}

__global__ void split_w2_kernel(const float* __restrict__ W2, bf16* __restrict__ Wh,
                                bf16* __restrict__ Wl) {
  int i = blockIdx.x * 256 + threadIdx.x;   // H2*H
  float v = W2[i];
  bf16 hi = (bf16)v;
  Wh[i] = hi;
  Wl[i] = (bf16)(v - (float)hi);
}

// -------- GEMM1 + fused LIF1 (ballot-packed, spill-free) -------------------

#define SA_OFF  0
#define SB0_OFF 16384
#define SB1_OFF 32768

__global__ __launch_bounds__(256, 2) void gemm1_lif1_kernel(
    const bf16* __restrict__ A, const bf16* __restrict__ B0,
    const bf16* __restrict__ B1, const float* __restrict__ bias,
    const float* __restrict__ beta1p,
    uint32_t* __restrict__ spkbits1, uint2* __restrict__ flag1,
    uint32_t* __restrict__ cnt1)
{
  __shared__ __align__(16) uint8_t lds[49152];
  const int tid = threadIdx.x;
  const int lane = tid & 63;
  const int wave = tid >> 6;
  const int wm = (wave >> 1) * 64, wn = (wave & 1) * 64;
  const size_t brow = (size_t)blockIdx.x * 128;
  const size_t bcol = (size_t)blockIdx.y * 128;
  const int K = 1024;
  const float be = clampf(beta1p[0]);

  const bf16* gA  = A  + brow * K;
  const bf16* gB0 = B0 + bcol * K;
  const bf16* gB1 = B1 + bcol * K;

  f32x4 acc[4][4] = {};

  for (int kk = 0; kk < K; kk += 64) {
#pragma unroll
    for (int q = 0; q < 4; ++q) {
      const int flat = q * 256 + tid;
      const int row = flat >> 3;
      const int s   = flat & 7;
      const int c8  = (s ^ (row & 7)) * 8;   // pre-swizzled source column
      gl16(gA  + (size_t)row * K + kk + c8, lds + SA_OFF  + flat * 16);
      gl16(gB0 + (size_t)row * K + kk + c8, lds + SB0_OFF + flat * 16);
      gl16(gB1 + (size_t)row * K + kk + c8, lds + SB1_OFF + flat * 16);
    }
    asm volatile("s_waitcnt vmcnt(0)" ::: "memory");
    __syncthreads();
#pragma unroll
    for (int ks = 0; ks < 2; ++ks) {
      bf16x8 af[4], b0f[4], b1f[4];
#pragma unroll
      for (int i = 0; i < 4; ++i) {
        const int ra = wm + i * 16 + (lane & 15);
        const int sa = ((ks * 4 + (lane >> 4)) ^ (ra & 7)) * 16;
        af[i]  = *(const bf16x8*)(lds + SA_OFF  + ra * 128 + sa);
        const int rb = wn + i * 16 + (lane & 15);
        const int sb = ((ks * 4 + (lane >> 4)) ^ (rb & 7)) * 16;
        b0f[i] = *(const bf16x8*)(lds + SB0_OFF + rb * 128 + sb);
        b1f[i] = *(const bf16x8*)(lds + SB1_OFF + rb * 128 + sb);
      }
#pragma unroll
      for (int m = 0; m < 4; ++m)
#pragma unroll
        for (int n = 0; n < 4; ++n) {
          acc[m][n] = __builtin_amdgcn_mfma_f32_16x16x32_bf16(af[m], b0f[n], acc[m][n], 0, 0, 0);
          acc[m][n] = __builtin_amdgcn_mfma_f32_16x16x32_bf16(af[m], b1f[n], acc[m][n], 0, 0, 0);
        }
    }
    __syncthreads();
  }

  // LIF1: element-outer (1 mem/hist live), ballot-packed bit output
  const int rg = lane >> 4;
  const bool writer = (lane & 15) == 0;
  uint16_t* sp16 = (uint16_t*)spkbits1;

#pragma unroll
  for (int m = 0; m < 4; ++m)
#pragma unroll
    for (int n = 0; n < 4; ++n) {
      const int chb = (int)(bcol) + wn + n * 16;   // wave-uniform col base
      const int w32 = chb >> 5, half = (chb >> 4) & 1;
      const float bv = bias[chb + (lane & 15)];
#pragma unroll
      for (int j = 0; j < 4; ++j) {
        const float c = acc[m][n][j] + bv;
        float mem = 0.f; uint32_t hist = 0; bool nearThr = false;
#pragma unroll
        for (int t = 0; t < 8; ++t) {
          float rst = (mem > 1.f) ? 1.f : 0.f;
          mem = be * mem + c - rst;
          uint32_t bit = (mem > 1.f) ? 1u : 0u;
          hist |= bit << t;
          nearThr |= (fabsf(mem - 1.f) < MARGIN);
        }
#pragma unroll
        for (int t = 0; t < 8; ++t) {
          unsigned long long bal = __ballot((hist >> t) & 1u);
          if (writer) {
            uint32_t row = (uint32_t)(brow + wm + m * 16 + rg * 4 + j);
            size_t idx = ((size_t)(t * 64 + w32) * 16384 + row) * 2 + half;
            sp16[idx] = (uint16_t)(bal >> (rg * 16));
          }
        }
        if (nearThr) {
          const uint32_t h = (uint32_t)(chb + (lane & 15));
          const uint32_t b = (uint32_t)(brow + wm + m * 16 + rg * 4 + j);
          uint32_t pos = atomicAdd(cnt1, 1u);
          if (pos < CAP1) { uint2 en; en.x = (h << 14) | b; en.y = hist; flag1[pos] = en; }
        }
      }
    }
}

// ------- repair1: f32 sequential-FMA (BLAS-order mimicry) redo -------------

__global__ __launch_bounds__(256) void repair1_kernel(
    const float* __restrict__ x, const float* __restrict__ W1,
    const float* __restrict__ b1, const float* __restrict__ beta1p,
    const uint2* __restrict__ flag1, const uint32_t* __restrict__ cnt1,
    uint32_t* __restrict__ spkbits1)
{
  uint32_t n = cnt1[0]; if (n > CAP1) n = CAP1;
  const float be = clampf(beta1p[0]);
  for (uint32_t i = blockIdx.x * 256 + threadIdx.x; i < n; i += gridDim.x * 256) {
    uint2 e = flag1[i];
    int h = e.x >> 14, b = e.x & 16383;
    const float* xr = x + (size_t)b * 512;
    const float* wr = W1 + (size_t)h * 512;
    float s = 0.f;                       // sgemm: sequential ascending-k FMA
    for (int d = 0; d < 512; ++d) s = fmaf(xr[d], wr[d], s);
    s = __fadd_rn(s, b1[h]);
    float m = 0.f; uint32_t eb = 0;
#pragma unroll
    for (int t = 0; t < 8; ++t) {
      float rst = (__fsub_rn(m, 1.f) > 0.f) ? 1.f : 0.f;
      m = __fsub_rn(__fadd_rn(__fmul_rn(be, m), s), rst);
      if (__fsub_rn(m, 1.f) > 0.f) eb |= 1u << t;
    }
    uint32_t diff = eb ^ (e.y & 0xFFu);
    if (diff) {
#pragma unroll
      for (int t = 0; t < 8; ++t)
        if ((diff >> t) & 1u)
          atomicXor(&spkbits1[((size_t)t * 64 + (h >> 5)) * 16384 + b], 1u << (h & 31));
    }
  }
}

// ---------------- step2: fused per-t GEMM + LIF2 (ballot-packed) -----------

__global__ __launch_bounds__(256, 2) void step2_kernel(
    const uint32_t* __restrict__ spkbits1,
    const bf16* __restrict__ W2h, const bf16* __restrict__ W2l,
    const float* __restrict__ b2, const float* __restrict__ beta2p,
    uint32_t* __restrict__ spkbits2, uint32_t* __restrict__ flag2,
    uint32_t* __restrict__ cnt2)
{
  __shared__ __align__(16) uint8_t lds[49152];
  const int K = 2048;
  const int tid = threadIdx.x;
  const int lane = tid & 63;
  const int wave = tid >> 6;
  const int wm = (wave >> 1) * 64, wn = (wave & 1) * 64;
  const size_t brow = (size_t)blockIdx.x * 128;
  const size_t bcol = (size_t)blockIdx.y * 128;
  const float be2 = clampf(beta2p[0]);

  const bf16* gB0 = W2h + bcol * K;
  const bf16* gB1 = W2l + bcol * K;

  float b2c[4];
#pragma unroll
  for (int n = 0; n < 4; ++n) b2c[n] = b2[bcol + wn + n * 16 + (lane & 15)];

  const int ar = tid & 127;
  const int aw = tid >> 7;
  const int rg = lane >> 4;
  const bool writer = (lane & 15) == 0;
  uint16_t* sp16 = (uint16_t*)spkbits2;

  f32x4 acc[4][4] = {};       // mem2, persistent across t
  unsigned long long flg = 0;

  for (int t = 0; t < 8; ++t) {
#pragma unroll
    for (int m = 0; m < 4; ++m)
#pragma unroll
      for (int n = 0; n < 4; ++n)
#pragma unroll
        for (int j = 0; j < 4; ++j) {
          float v = acc[m][n][j];
          float rst = (v > 1.f) ? 1.f : 0.f;
          acc[m][n][j] = be2 * v + (b2c[n] - rst);
        }

    for (int kk = 0; kk < K; kk += 64) {
      uint32_t bits = spkbits1[((size_t)t * 64 + (kk >> 5) + aw) * 16384 + brow + ar];
#pragma unroll
      for (int c = 0; c < 4; ++c) {
        uint4 u;
        u.x = expand2(bits >> (8 * c));
        u.y = expand2(bits >> (8 * c + 2));
        u.z = expand2(bits >> (8 * c + 4));
        u.w = expand2(bits >> (8 * c + 6));
        const int slot = (aw * 4 + c) ^ (ar & 7);
        *(uint4*)(lds + SA_OFF + ar * 128 + slot * 16) = u;
      }
#pragma unroll
      for (int q = 0; q < 4; ++q) {
        const int flat = q * 256 + tid;
        const int row = flat >> 3;
        const int s   = flat & 7;
        const int c8  = (s ^ (row & 7)) * 8;   // pre-swizzled source column
        gl16(gB0 + (size_t)row * K + kk + c8, lds + SB0_OFF + flat * 16);
        gl16(gB1 + (size_t)row * K + kk + c8, lds + SB1_OFF + flat * 16);
      }
      asm volatile("s_waitcnt vmcnt(0)" ::: "memory");
      __syncthreads();
#pragma unroll
      for (int ks = 0; ks < 2; ++ks) {
        bf16x8 af[4], b0f[4], b1f[4];
#pragma unroll
        for (int i = 0; i < 4; ++i) {
          const int ra = wm + i * 16 + (lane & 15);
          const int sa = ((ks * 4 + (lane >> 4)) ^ (ra & 7)) * 16;
          af[i] = *(const bf16x8*)(lds + SA_OFF + ra * 128 + sa);
          const int rb = wn + i * 16 + (lane & 15);
          const int sb = ((ks * 4 + (lane >> 4)) ^ (rb & 7)) * 16;
          b0f[i] = *(const bf16x8*)(lds + SB0_OFF + rb * 128 + sb);
          b1f[i] = *(const bf16x8*)(lds + SB1_OFF + rb * 128 + sb);
        }
#pragma unroll
        for (int m = 0; m < 4; ++m)
#pragma unroll
          for (int n = 0; n < 4; ++n) {
            acc[m][n] = __builtin_amdgcn_mfma_f32_16x16x32_bf16(af[m], b0f[n], acc[m][n], 0, 0, 0);
            acc[m][n] = __builtin_amdgcn_mfma_f32_16x16x32_bf16(af[m], b1f[n], acc[m][n], 0, 0, 0);
          }
      }
      __syncthreads();
    }

    // spike bits via ballot (register-only; no barriers)
#pragma unroll
    for (int m = 0; m < 4; ++m)
#pragma unroll
      for (int n = 0; n < 4; ++n) {
        const int chb = (int)(bcol) + wn + n * 16;
        const int w32 = chb >> 5, half = (chb >> 4) & 1;
#pragma unroll
        for (int j = 0; j < 4; ++j) {
          float v = acc[m][n][j];
          if (fabsf(v - 1.f) < MARGIN) flg |= 1ull << (m * 16 + n * 4 + j);
          unsigned long long bal = __ballot(v > 1.f);
          if (writer) {
            uint32_t row = (uint32_t)(brow + wm + m * 16 + rg * 4 + j);
            size_t idx = ((size_t)(t * 32 + w32) * 16384 + row) * 2 + half;
            sp16[idx] = (uint16_t)(bal >> (rg * 16));
          }
        }
      }
  }

  if (flg) {
#pragma unroll
    for (int m = 0; m < 4; ++m)
#pragma unroll
      for (int n = 0; n < 4; ++n)
#pragma unroll
        for (int j = 0; j < 4; ++j)
          if ((flg >> (m * 16 + n * 4 + j)) & 1ull) {
            const int row = wm + m * 16 + rg * 4 + j;
            const int col = wn + n * 16 + (lane & 15);
            uint32_t pos = atomicAdd(cnt2, 1u);
            if (pos < CAP2)
              flag2[pos] = (uint32_t)(((brow + row) << 10) | (bcol + col));
          }
  }
}

// ------- repair2: f32 sequential-FMA (BLAS-order mimicry) redo -------------

__global__ __launch_bounds__(256) void repair2_kernel(
    const uint32_t* __restrict__ spkbits1, const float* __restrict__ W2,
    const float* __restrict__ b2, const float* __restrict__ beta2p,
    const uint32_t* __restrict__ flag2, const uint32_t* __restrict__ cnt2,
    uint32_t* __restrict__ spkbits2)
{
  uint32_t n = cnt2[0]; if (n > CAP2) n = CAP2;
  const float be = clampf(beta2p[0]);
  for (uint32_t i = blockIdx.x * 256 + threadIdx.x; i < n; i += gridDim.x * 256) {
    uint32_t e = flag2[i];
    int b = e >> 10, h2 = e & 1023;
    const float* wr = W2 + (size_t)h2 * 2048;
    const float bias = b2[h2];
    float m = 0.f;
    for (int t = 0; t < 8; ++t) {
      float s = 0.f;   // fma(spk,w,c): spk=1 -> RN(w+c); spk=0 -> exact skip
      for (int w = 0; w < 64; ++w) {
        uint32_t bits = spkbits1[((size_t)t * 64 + w) * 16384 + b];
        while (bits) {
          int k = __builtin_ctz(bits);
          bits &= bits - 1;
          s = __fadd_rn(s, wr[w * 32 + k]);
        }
      }
      s = __fadd_rn(s, bias);
      float rst = (__fsub_rn(m, 1.f) > 0.f) ? 1.f : 0.f;
      m = __fsub_rn(__fadd_rn(__fmul_rn(be, m), s), rst);
      uint32_t exact = (__fsub_rn(m, 1.f) > 0.f) ? 1u : 0u;
      uint32_t* wp = &spkbits2[((size_t)t * 32 + (h2 >> 5)) * 16384 + b];
      uint32_t stored = (*wp >> (h2 & 31)) & 1u;
      if (stored != exact) atomicXor(wp, 1u << (h2 & 31));
    }
  }
}

// ---------------- output: f64 mem_out recurrence + max from spike bits -----

__global__ __launch_bounds__(256) void out_kernel(
    const uint32_t* __restrict__ spkbits2, const float* __restrict__ Wo,
    const float* __restrict__ bo, const float* __restrict__ betaop,
    float* __restrict__ out)
{
  const int wave = threadIdx.x >> 6, lane = threadIdx.x & 63;
  const int b = blockIdx.x * 4 + wave;
  const double beo = (double)clampf(betaop[0]);
  const int wrd = lane >> 1;
  const int half = lane & 1;
  const int h2base = lane * 16;
  double mo[8] = {0, 0, 0, 0, 0, 0, 0, 0};
  double mx[8];
#pragma unroll
  for (int a = 0; a < 8; ++a) mx[a] = -1e9;
  for (int t = 0; t < 8; ++t) {
    uint32_t word = spkbits2[((size_t)t * 32 + wrd) * 16384 + b];
    uint32_t bits = (word >> (half * 16)) & 0xFFFFu;
    double s[8] = {0, 0, 0, 0, 0, 0, 0, 0};
#pragma unroll
    for (int k = 0; k < 16; ++k) {
      if ((bits >> k) & 1u) {
#pragma unroll
        for (int a = 0; a < 8; ++a)
          s[a] += (double)Wo[a * 1024 + h2base + k];
      }
    }
#pragma unroll
    for (int a = 0; a < 8; ++a)
#pragma unroll
      for (int off = 32; off > 0; off >>= 1)
        s[a] += __shfl_down(s[a], off, 64);
    if (lane == 0) {
#pragma unroll
      for (int a = 0; a < 8; ++a) {
        mo[a] = beo * mo[a] + (s[a] + (double)bo[a]);
        mx[a] = fmax(mx[a], mo[a]);
      }
    }
  }
  if (lane == 0) {
#pragma unroll
    for (int a = 0; a < 8; ++a)
      out[(size_t)b * 8 + a] = (float)mx[a];
  }
}

__global__ void zero_hdr_kernel(uint32_t* p) {
  if (threadIdx.x < 64) p[threadIdx.x] = 0;
}

__global__ void fill_sentinel(float* out, int n, float v) {
  int i = blockIdx.x * 256 + threadIdx.x;
  if (i < n) out[i] = v;
}

// ---------------- launch ----------------

extern "C" void kernel_launch(void* const* d_in, const int* in_sizes, int n_in,
                              void* d_out, int out_size, void* d_ws, size_t ws_size,
                              hipStream_t stream)
{
  (void)in_sizes; (void)n_in;
  const float* x   = (const float*)d_in[0];
  const float* W1  = (const float*)d_in[1];
  const float* b1  = (const float*)d_in[2];
  const float* W2  = (const float*)d_in[3];
  const float* b2  = (const float*)d_in[4];
  const float* Wo  = (const float*)d_in[5];
  const float* bo  = (const float*)d_in[6];
  const float* be1 = (const float*)d_in[7];
  const float* be2 = (const float*)d_in[8];
  const float* beo = (const float*)d_in[9];
  float* out = (float*)d_out;

  const int B = 16384, D = 512, H = 2048, H2 = 1024;

  const size_t sz_hdr  = 256;
  const size_t sz_Ax   = (size_t)B * 1024 * 2;        // 32 MB
  const size_t sz_W1s  = (size_t)H * 1024 * 2;        // 4 MB each
  const size_t sz_W2s  = (size_t)H2 * H * 2;          // 4 MB each
  const size_t sz_b1   = (size_t)8 * 64 * B * 4;      // 32 MB
  const size_t sz_b2   = (size_t)8 * 32 * B * 4;      // 16 MB
  const size_t sz_f1   = (size_t)CAP1 * 8;            // 16 MB
  const size_t sz_f2   = (size_t)CAP2 * 4;            // 8 MB
  const size_t need = sz_hdr + sz_Ax + 2 * sz_W1s + 2 * sz_W2s +
                      sz_b1 + sz_b2 + sz_f1 + sz_f2;  // ~120 MB

  if (ws_size < need) {
    fill_sentinel<<<(out_size + 255) / 256, 256, 0, stream>>>(
        out, out_size, 1000.0f + (float)(ws_size >> 20));
    return;
  }

  uint8_t* p = (uint8_t*)d_ws;
  uint32_t* hdr = (uint32_t*)p;     p += sz_hdr;
  bf16* Ax      = (bf16*)p;         p += sz_Ax;
  bf16* W1B0    = (bf16*)p;         p += sz_W1s;
  bf16* W1B1    = (bf16*)p;         p += sz_W1s;
  bf16* W2h     = (bf16*)p;         p += sz_W2s;
  bf16* W2l     = (bf16*)p;         p += sz_W2s;
  uint32_t* spkbits1 = (uint32_t*)p; p += sz_b1;
  uint32_t* spkbits2 = (uint32_t*)p; p += sz_b2;
  uint2* flag1  = (uint2*)p;        p += sz_f1;
  uint32_t* flag2 = (uint32_t*)p;   p += sz_f2;
  uint32_t* cnt1 = hdr + 0;
  uint32_t* cnt2 = hdr + 1;

  zero_hdr_kernel<<<1, 64, 0, stream>>>(hdr);
  split_x_kernel <<<(B * D) / 256, 256, 0, stream>>>(x, Ax);
  split_w1_kernel<<<(H * D) / 256, 256, 0, stream>>>(W1, W1B0, W1B1);
  split_w2_kernel<<<(H2 * H) / 256, 256, 0, stream>>>(W2, W2h, W2l);

  gemm1_lif1_kernel<<<dim3(B / 128, H / 128), 256, 0, stream>>>(
      Ax, W1B0, W1B1, b1, be1, spkbits1, flag1, cnt1);
  repair1_kernel<<<256, 256, 0, stream>>>(x, W1, b1, be1, flag1, cnt1, spkbits1);

  step2_kernel<<<dim3(B / 128, H2 / 128), 256, 0, stream>>>(
      spkbits1, W2h, W2l, b2, be2, spkbits2, flag2, cnt2);
  repair2_kernel<<<256, 256, 0, stream>>>(spkbits1, W2, b2, be2, flag2, cnt2, spkbits2);

  out_kernel<<<B / 4, 256, 0, stream>>>(spkbits2, Wo, bo, beo, out);
}

// Round 7
// 4500.987 us; speedup vs baseline: 1.8748x; 1.8521x over previous
//
#include <hip/hip_runtime.h>
#include <stdint.h>

// SpikingQNetwork B=16384 D=512 H=2048 H2=1024 A=8 T=8.
// Fast path: bf16 2-term-split MFMA GEMMs; near-threshold neurons repaired
// with f32 sequential-FMA (BLAS mimicry); spike bits patched via atomicXor.
// R6->R7: hierarchical flag collection (per-block LDS list + ONE global
// atomic per block) replacing per-element same-address global atomics --
// the suspected fixed serial resource making both GEMM kernels ~99% idle.

typedef __bf16 bf16;
typedef __attribute__((ext_vector_type(8))) __bf16 bf16x8;
typedef __attribute__((ext_vector_type(4))) float f32x4;

#define CAP1 2097152
#define CAP2 2097152
#define MARGIN 2e-3f

__device__ __forceinline__ void gl16(const void* g, void* l) {
  __builtin_amdgcn_global_load_lds(
      (const __attribute__((address_space(1))) uint32_t*)g,
      (__attribute__((address_space(3))) uint32_t*)l, 16, 0, 0);
}

__device__ __forceinline__ float clampf(float v) {
  return fminf(fmaxf(v, 0.f), 1.f);
}

__device__ __forceinline__ uint32_t expand2(uint32_t b) {
  // 2 spike bits -> 2 packed bf16 (1.0 = 0x3F80)
  return ((b & 1u) ? 0x3F80u : 0u) | ((b & 2u) ? 0x3F800000u : 0u);
}

// ---------------- splits (bf16 hi/lo) -------------------------------------

__global__ void split_x_kernel(const float* __restrict__ x, bf16* __restrict__ Ax) {
  int i = blockIdx.x * 256 + threadIdx.x;   // B*D
  int b = i >> 9, d = i & 511;
  float v = x[i];
  bf16 hi = (bf16)v;
  bf16 lo = (bf16)(v - (float)hi);
  size_t base = (size_t)b * 1024;
  Ax[base + d] = hi;
  Ax[base + 512 + d] = lo;
}

__global__ void split_w1_kernel(const float* __restrict__ W1, bf16* __restrict__ B0,
                                bf16* __restrict__ B1) {
  int i = blockIdx.x * 256 + threadIdx.x;   // H*D
  int r = i >> 9, d = i & 511;
  float v = W1[i];
  bf16 hi = (bf16)v;
  bf16 lo = (bf16)(v - (float)hi);
  size_t base = (size_t)r * 1024;
  B0[base + d] = hi;  B0[base + 512 + d] = lo;   // [w0|w1]
  B1[base + d] = lo;  B1[base + 512 + d] = hi;   // [w1|w0]
}

__global__ void split_w2_kernel(const float* __restrict__ W2, bf16* __restrict__ Wh,
                                bf16* __restrict__ Wl) {
  int i = blockIdx.x * 256 + threadIdx.x;   // H2*H
  float v = W2[i];
  bf16 hi = (bf16)v;
  Wh[i] = hi;
  Wl[i] = (bf16)(v - (float)hi);
}

// -------- GEMM1 + fused LIF1 (ballot-packed, hierarchical flags) ----------

#define SA_OFF  0
#define SB0_OFF 16384
#define SB1_OFF 32768

__global__ __launch_bounds__(256, 2) void gemm1_lif1_kernel(
    const bf16* __restrict__ A, const bf16* __restrict__ B0,
    const bf16* __restrict__ B1, const float* __restrict__ bias,
    const float* __restrict__ beta1p,
    uint32_t* __restrict__ spkbits1, uint2* __restrict__ flag1,
    uint32_t* __restrict__ cnt1)
{
  __shared__ __align__(16) uint8_t lds[49152];
  const int tid = threadIdx.x;
  const int lane = tid & 63;
  const int wave = tid >> 6;
  const int wm = (wave >> 1) * 64, wn = (wave & 1) * 64;
  const size_t brow = (size_t)blockIdx.x * 128;
  const size_t bcol = (size_t)blockIdx.y * 128;
  const int K = 1024;
  const float be = clampf(beta1p[0]);

  const bf16* gA  = A  + brow * K;
  const bf16* gB0 = B0 + bcol * K;
  const bf16* gB1 = B1 + bcol * K;

  f32x4 acc[4][4] = {};

  for (int kk = 0; kk < K; kk += 64) {
#pragma unroll
    for (int q = 0; q < 4; ++q) {
      const int flat = q * 256 + tid;
      const int row = flat >> 3;
      const int s   = flat & 7;
      const int c8  = (s ^ (row & 7)) * 8;   // pre-swizzled source column
      gl16(gA  + (size_t)row * K + kk + c8, lds + SA_OFF  + flat * 16);
      gl16(gB0 + (size_t)row * K + kk + c8, lds + SB0_OFF + flat * 16);
      gl16(gB1 + (size_t)row * K + kk + c8, lds + SB1_OFF + flat * 16);
    }
    asm volatile("s_waitcnt vmcnt(0)" ::: "memory");
    __syncthreads();
#pragma unroll
    for (int ks = 0; ks < 2; ++ks) {
      bf16x8 af[4], b0f[4], b1f[4];
#pragma unroll
      for (int i = 0; i < 4; ++i) {
        const int ra = wm + i * 16 + (lane & 15);
        const int sa = ((ks * 4 + (lane >> 4)) ^ (ra & 7)) * 16;
        af[i]  = *(const bf16x8*)(lds + SA_OFF  + ra * 128 + sa);
        const int rb = wn + i * 16 + (lane & 15);
        const int sb = ((ks * 4 + (lane >> 4)) ^ (rb & 7)) * 16;
        b0f[i] = *(const bf16x8*)(lds + SB0_OFF + rb * 128 + sb);
        b1f[i] = *(const bf16x8*)(lds + SB1_OFF + rb * 128 + sb);
      }
#pragma unroll
      for (int m = 0; m < 4; ++m)
#pragma unroll
        for (int n = 0; n < 4; ++n) {
          acc[m][n] = __builtin_amdgcn_mfma_f32_16x16x32_bf16(af[m], b0f[n], acc[m][n], 0, 0, 0);
          acc[m][n] = __builtin_amdgcn_mfma_f32_16x16x32_bf16(af[m], b1f[n], acc[m][n], 0, 0, 0);
        }
    }
    __syncthreads();
  }

  // LDS reuse: flag list (tiles dead after K-loop's final barrier)
  uint32_t* lcnt  = (uint32_t*)lds;            // [0]
  uint32_t* lbase = (uint32_t*)(lds + 4);      // [1]
  uint2*    llist = (uint2*)(lds + 16);
  const uint32_t CAPL = 3000;
  if (tid == 0) *lcnt = 0;
  __syncthreads();

  // LIF1: element-outer (1 mem/hist live), ballot-packed bit output
  const int rg = lane >> 4;
  const bool writer = (lane & 15) == 0;
  uint16_t* sp16 = (uint16_t*)spkbits1;

#pragma unroll
  for (int m = 0; m < 4; ++m)
#pragma unroll
    for (int n = 0; n < 4; ++n) {
      const int chb = (int)(bcol) + wn + n * 16;   // wave-uniform col base
      const int w32 = chb >> 5, half = (chb >> 4) & 1;
      const float bv = bias[chb + (lane & 15)];
#pragma unroll
      for (int j = 0; j < 4; ++j) {
        const float c = acc[m][n][j] + bv;
        float mem = 0.f; uint32_t hist = 0; bool nearThr = false;
#pragma unroll
        for (int t = 0; t < 8; ++t) {
          float rst = (mem > 1.f) ? 1.f : 0.f;
          mem = be * mem + c - rst;
          uint32_t bit = (mem > 1.f) ? 1u : 0u;
          hist |= bit << t;
          nearThr |= (fabsf(mem - 1.f) < MARGIN);
        }
#pragma unroll
        for (int t = 0; t < 8; ++t) {
          unsigned long long bal = __ballot((hist >> t) & 1u);
          if (writer) {
            uint32_t row = (uint32_t)(brow + wm + m * 16 + rg * 4 + j);
            size_t idx = ((size_t)(t * 64 + w32) * 16384 + row) * 2 + half;
            sp16[idx] = (uint16_t)(bal >> (rg * 16));
          }
        }
        if (nearThr) {
          const uint32_t h = (uint32_t)(chb + (lane & 15));
          const uint32_t b = (uint32_t)(brow + wm + m * 16 + rg * 4 + j);
          uint2 en; en.x = (h << 14) | b; en.y = hist;
          uint32_t pos = atomicAdd(lcnt, 1u);
          if (pos < CAPL) llist[pos] = en;
          else { uint32_t g = atomicAdd(cnt1, 1u); if (g < CAP1) flag1[g] = en; }
        }
      }
    }

  __syncthreads();
  uint32_t ln = *lcnt; if (ln > CAPL) ln = CAPL;
  if (tid == 0) *lbase = atomicAdd(cnt1, ln);
  __syncthreads();
  const uint32_t gb = *lbase;
  for (uint32_t i = tid; i < ln; i += 256) {
    uint32_t g = gb + i;
    if (g < CAP1) flag1[g] = llist[i];
  }
}

// ------- repair1: f32 sequential-FMA (BLAS-order mimicry) redo -------------

__global__ __launch_bounds__(256) void repair1_kernel(
    const float* __restrict__ x, const float* __restrict__ W1,
    const float* __restrict__ b1, const float* __restrict__ beta1p,
    const uint2* __restrict__ flag1, const uint32_t* __restrict__ cnt1,
    uint32_t* __restrict__ spkbits1)
{
  uint32_t n = cnt1[0]; if (n > CAP1) n = CAP1;
  const float be = clampf(beta1p[0]);
  for (uint32_t i = blockIdx.x * 256 + threadIdx.x; i < n; i += gridDim.x * 256) {
    uint2 e = flag1[i];
    int h = e.x >> 14, b = e.x & 16383;
    const float* xr = x + (size_t)b * 512;
    const float* wr = W1 + (size_t)h * 512;
    float s = 0.f;                       // sgemm: sequential ascending-k FMA
    for (int d = 0; d < 512; ++d) s = fmaf(xr[d], wr[d], s);
    s = __fadd_rn(s, b1[h]);
    float m = 0.f; uint32_t eb = 0;
#pragma unroll
    for (int t = 0; t < 8; ++t) {
      float rst = (__fsub_rn(m, 1.f) > 0.f) ? 1.f : 0.f;
      m = __fsub_rn(__fadd_rn(__fmul_rn(be, m), s), rst);
      if (__fsub_rn(m, 1.f) > 0.f) eb |= 1u << t;
    }
    uint32_t diff = eb ^ (e.y & 0xFFu);
    if (diff) {
#pragma unroll
      for (int t = 0; t < 8; ++t)
        if ((diff >> t) & 1u)
          atomicXor(&spkbits1[((size_t)t * 64 + (h >> 5)) * 16384 + b], 1u << (h & 31));
    }
  }
}

// ------- step2: fused per-t GEMM + LIF2 (ballot-packed, hier flags) --------

__global__ __launch_bounds__(256, 2) void step2_kernel(
    const uint32_t* __restrict__ spkbits1,
    const bf16* __restrict__ W2h, const bf16* __restrict__ W2l,
    const float* __restrict__ b2, const float* __restrict__ beta2p,
    uint32_t* __restrict__ spkbits2, uint32_t* __restrict__ flag2,
    uint32_t* __restrict__ cnt2)
{
  __shared__ __align__(16) uint8_t lds[49152];
  const int K = 2048;
  const int tid = threadIdx.x;
  const int lane = tid & 63;
  const int wave = tid >> 6;
  const int wm = (wave >> 1) * 64, wn = (wave & 1) * 64;
  const size_t brow = (size_t)blockIdx.x * 128;
  const size_t bcol = (size_t)blockIdx.y * 128;
  const float be2 = clampf(beta2p[0]);

  const bf16* gB0 = W2h + bcol * K;
  const bf16* gB1 = W2l + bcol * K;

  float b2c[4];
#pragma unroll
  for (int n = 0; n < 4; ++n) b2c[n] = b2[bcol + wn + n * 16 + (lane & 15)];

  const int ar = tid & 127;
  const int aw = tid >> 7;
  const int rg = lane >> 4;
  const bool writer = (lane & 15) == 0;
  uint16_t* sp16 = (uint16_t*)spkbits2;

  f32x4 acc[4][4] = {};       // mem2, persistent across t
  unsigned long long flg = 0;

  for (int t = 0; t < 8; ++t) {
#pragma unroll
    for (int m = 0; m < 4; ++m)
#pragma unroll
      for (int n = 0; n < 4; ++n)
#pragma unroll
        for (int j = 0; j < 4; ++j) {
          float v = acc[m][n][j];
          float rst = (v > 1.f) ? 1.f : 0.f;
          acc[m][n][j] = be2 * v + (b2c[n] - rst);
        }

    for (int kk = 0; kk < K; kk += 64) {
      uint32_t bits = spkbits1[((size_t)t * 64 + (kk >> 5) + aw) * 16384 + brow + ar];
#pragma unroll
      for (int c = 0; c < 4; ++c) {
        uint4 u;
        u.x = expand2(bits >> (8 * c));
        u.y = expand2(bits >> (8 * c + 2));
        u.z = expand2(bits >> (8 * c + 4));
        u.w = expand2(bits >> (8 * c + 6));
        const int slot = (aw * 4 + c) ^ (ar & 7);
        *(uint4*)(lds + SA_OFF + ar * 128 + slot * 16) = u;
      }
#pragma unroll
      for (int q = 0; q < 4; ++q) {
        const int flat = q * 256 + tid;
        const int row = flat >> 3;
        const int s   = flat & 7;
        const int c8  = (s ^ (row & 7)) * 8;   // pre-swizzled source column
        gl16(gB0 + (size_t)row * K + kk + c8, lds + SB0_OFF + flat * 16);
        gl16(gB1 + (size_t)row * K + kk + c8, lds + SB1_OFF + flat * 16);
      }
      asm volatile("s_waitcnt vmcnt(0)" ::: "memory");
      __syncthreads();
#pragma unroll
      for (int ks = 0; ks < 2; ++ks) {
        bf16x8 af[4], b0f[4], b1f[4];
#pragma unroll
        for (int i = 0; i < 4; ++i) {
          const int ra = wm + i * 16 + (lane & 15);
          const int sa = ((ks * 4 + (lane >> 4)) ^ (ra & 7)) * 16;
          af[i] = *(const bf16x8*)(lds + SA_OFF + ra * 128 + sa);
          const int rb = wn + i * 16 + (lane & 15);
          const int sb = ((ks * 4 + (lane >> 4)) ^ (rb & 7)) * 16;
          b0f[i] = *(const bf16x8*)(lds + SB0_OFF + rb * 128 + sb);
          b1f[i] = *(const bf16x8*)(lds + SB1_OFF + rb * 128 + sb);
        }
#pragma unroll
        for (int m = 0; m < 4; ++m)
#pragma unroll
          for (int n = 0; n < 4; ++n) {
            acc[m][n] = __builtin_amdgcn_mfma_f32_16x16x32_bf16(af[m], b0f[n], acc[m][n], 0, 0, 0);
            acc[m][n] = __builtin_amdgcn_mfma_f32_16x16x32_bf16(af[m], b1f[n], acc[m][n], 0, 0, 0);
          }
      }
      __syncthreads();
    }

    // spike bits via ballot (register-only; no barriers)
#pragma unroll
    for (int m = 0; m < 4; ++m)
#pragma unroll
      for (int n = 0; n < 4; ++n) {
        const int chb = (int)(bcol) + wn + n * 16;
        const int w32 = chb >> 5, half = (chb >> 4) & 1;
#pragma unroll
        for (int j = 0; j < 4; ++j) {
          float v = acc[m][n][j];
          if (fabsf(v - 1.f) < MARGIN) flg |= 1ull << (m * 16 + n * 4 + j);
          unsigned long long bal = __ballot(v > 1.f);
          if (writer) {
            uint32_t row = (uint32_t)(brow + wm + m * 16 + rg * 4 + j);
            size_t idx = ((size_t)(t * 32 + w32) * 16384 + row) * 2 + half;
            sp16[idx] = (uint16_t)(bal >> (rg * 16));
          }
        }
      }
  }

  // hierarchical flag collection (LDS tiles dead)
  uint32_t* lcnt  = (uint32_t*)lds;
  uint32_t* lbase = (uint32_t*)(lds + 4);
  uint32_t* llist = (uint32_t*)(lds + 16);
  const uint32_t CAPL = 6000;
  if (tid == 0) *lcnt = 0;
  __syncthreads();

  if (flg) {
#pragma unroll
    for (int m = 0; m < 4; ++m)
#pragma unroll
      for (int n = 0; n < 4; ++n)
#pragma unroll
        for (int j = 0; j < 4; ++j)
          if ((flg >> (m * 16 + n * 4 + j)) & 1ull) {
            const int row = wm + m * 16 + rg * 4 + j;
            const int col = wn + n * 16 + (lane & 15);
            uint32_t en = (uint32_t)(((brow + row) << 10) | (bcol + col));
            uint32_t pos = atomicAdd(lcnt, 1u);
            if (pos < CAPL) llist[pos] = en;
            else { uint32_t g = atomicAdd(cnt2, 1u); if (g < CAP2) flag2[g] = en; }
          }
  }

  __syncthreads();
  uint32_t ln = *lcnt; if (ln > CAPL) ln = CAPL;
  if (tid == 0) *lbase = atomicAdd(cnt2, ln);
  __syncthreads();
  const uint32_t gb = *lbase;
  for (uint32_t i = tid; i < ln; i += 256) {
    uint32_t g = gb + i;
    if (g < CAP2) flag2[g] = llist[i];
  }
}

// ------- repair2: f32 sequential-FMA (BLAS-order mimicry) redo -------------

__global__ __launch_bounds__(256) void repair2_kernel(
    const uint32_t* __restrict__ spkbits1, const float* __restrict__ W2,
    const float* __restrict__ b2, const float* __restrict__ beta2p,
    const uint32_t* __restrict__ flag2, const uint32_t* __restrict__ cnt2,
    uint32_t* __restrict__ spkbits2)
{
  uint32_t n = cnt2[0]; if (n > CAP2) n = CAP2;
  const float be = clampf(beta2p[0]);
  for (uint32_t i = blockIdx.x * 256 + threadIdx.x; i < n; i += gridDim.x * 256) {
    uint32_t e = flag2[i];
    int b = e >> 10, h2 = e & 1023;
    const float* wr = W2 + (size_t)h2 * 2048;
    const float bias = b2[h2];
    float m = 0.f;
    for (int t = 0; t < 8; ++t) {
      float s = 0.f;   // fma(spk,w,c): spk=1 -> RN(w+c); spk=0 -> exact skip
      for (int w = 0; w < 64; ++w) {
        uint32_t bits = spkbits1[((size_t)t * 64 + w) * 16384 + b];
        while (bits) {
          int k = __builtin_ctz(bits);
          bits &= bits - 1;
          s = __fadd_rn(s, wr[w * 32 + k]);
        }
      }
      s = __fadd_rn(s, bias);
      float rst = (__fsub_rn(m, 1.f) > 0.f) ? 1.f : 0.f;
      m = __fsub_rn(__fadd_rn(__fmul_rn(be, m), s), rst);
      uint32_t exact = (__fsub_rn(m, 1.f) > 0.f) ? 1u : 0u;
      uint32_t* wp = &spkbits2[((size_t)t * 32 + (h2 >> 5)) * 16384 + b];
      uint32_t stored = (*wp >> (h2 & 31)) & 1u;
      if (stored != exact) atomicXor(wp, 1u << (h2 & 31));
    }
  }
}

// ---------------- output: f64 mem_out recurrence + max from spike bits -----

__global__ __launch_bounds__(256) void out_kernel(
    const uint32_t* __restrict__ spkbits2, const float* __restrict__ Wo,
    const float* __restrict__ bo, const float* __restrict__ betaop,
    float* __restrict__ out)
{
  const int wave = threadIdx.x >> 6, lane = threadIdx.x & 63;
  const int b = blockIdx.x * 4 + wave;
  const double beo = (double)clampf(betaop[0]);
  const int wrd = lane >> 1;
  const int half = lane & 1;
  const int h2base = lane * 16;
  double mo[8] = {0, 0, 0, 0, 0, 0, 0, 0};
  double mx[8];
#pragma unroll
  for (int a = 0; a < 8; ++a) mx[a] = -1e9;
  for (int t = 0; t < 8; ++t) {
    uint32_t word = spkbits2[((size_t)t * 32 + wrd) * 16384 + b];
    uint32_t bits = (word >> (half * 16)) & 0xFFFFu;
    double s[8] = {0, 0, 0, 0, 0, 0, 0, 0};
#pragma unroll
    for (int k = 0; k < 16; ++k) {
      if ((bits >> k) & 1u) {
#pragma unroll
        for (int a = 0; a < 8; ++a)
          s[a] += (double)Wo[a * 1024 + h2base + k];
      }
    }
#pragma unroll
    for (int a = 0; a < 8; ++a)
#pragma unroll
      for (int off = 32; off > 0; off >>= 1)
        s[a] += __shfl_down(s[a], off, 64);
    if (lane == 0) {
#pragma unroll
      for (int a = 0; a < 8; ++a) {
        mo[a] = beo * mo[a] + (s[a] + (double)bo[a]);
        mx[a] = fmax(mx[a], mo[a]);
      }
    }
  }
  if (lane == 0) {
#pragma unroll
    for (int a = 0; a < 8; ++a)
      out[(size_t)b * 8 + a] = (float)mx[a];
  }
}

__global__ void zero_hdr_kernel(uint32_t* p) {
  if (threadIdx.x < 64) p[threadIdx.x] = 0;
}

__global__ void fill_sentinel(float* out, int n, float v) {
  int i = blockIdx.x * 256 + threadIdx.x;
  if (i < n) out[i] = v;
}

// ---------------- launch ----------------

extern "C" void kernel_launch(void* const* d_in, const int* in_sizes, int n_in,
                              void* d_out, int out_size, void* d_ws, size_t ws_size,
                              hipStream_t stream)
{
  (void)in_sizes; (void)n_in;
  const float* x   = (const float*)d_in[0];
  const float* W1  = (const float*)d_in[1];
  const float* b1  = (const float*)d_in[2];
  const float* W2  = (const float*)d_in[3];
  const float* b2  = (const float*)d_in[4];
  const float* Wo  = (const float*)d_in[5];
  const float* bo  = (const float*)d_in[6];
  const float* be1 = (const float*)d_in[7];
  const float* be2 = (const float*)d_in[8];
  const float* beo = (const float*)d_in[9];
  float* out = (float*)d_out;

  const int B = 16384, D = 512, H = 2048, H2 = 1024;

  const size_t sz_hdr  = 256;
  const size_t sz_Ax   = (size_t)B * 1024 * 2;        // 32 MB
  const size_t sz_W1s  = (size_t)H * 1024 * 2;        // 4 MB each
  const size_t sz_W2s  = (size_t)H2 * H * 2;          // 4 MB each
  const size_t sz_b1   = (size_t)8 * 64 * B * 4;      // 32 MB
  const size_t sz_b2   = (size_t)8 * 32 * B * 4;      // 16 MB
  const size_t sz_f1   = (size_t)CAP1 * 8;            // 16 MB
  const size_t sz_f2   = (size_t)CAP2 * 4;            // 8 MB
  const size_t need = sz_hdr + sz_Ax + 2 * sz_W1s + 2 * sz_W2s +
                      sz_b1 + sz_b2 + sz_f1 + sz_f2;  // ~120 MB

  if (ws_size < need) {
    fill_sentinel<<<(out_size + 255) / 256, 256, 0, stream>>>(
        out, out_size, 1000.0f + (float)(ws_size >> 20));
    return;
  }

  uint8_t* p = (uint8_t*)d_ws;
  uint32_t* hdr = (uint32_t*)p;     p += sz_hdr;
  bf16* Ax      = (bf16*)p;         p += sz_Ax;
  bf16* W1B0    = (bf16*)p;         p += sz_W1s;
  bf16* W1B1    = (bf16*)p;         p += sz_W1s;
  bf16* W2h     = (bf16*)p;         p += sz_W2s;
  bf16* W2l     = (bf16*)p;         p += sz_W2s;
  uint32_t* spkbits1 = (uint32_t*)p; p += sz_b1;
  uint32_t* spkbits2 = (uint32_t*)p; p += sz_b2;
  uint2* flag1  = (uint2*)p;        p += sz_f1;
  uint32_t* flag2 = (uint32_t*)p;   p += sz_f2;
  uint32_t* cnt1 = hdr + 0;
  uint32_t* cnt2 = hdr + 1;

  zero_hdr_kernel<<<1, 64, 0, stream>>>(hdr);
  split_x_kernel <<<(B * D) / 256, 256, 0, stream>>>(x, Ax);
  split_w1_kernel<<<(H * D) / 256, 256, 0, stream>>>(W1, W1B0, W1B1);
  split_w2_kernel<<<(H2 * H) / 256, 256, 0, stream>>>(W2, W2h, W2l);

  gemm1_lif1_kernel<<<dim3(B / 128, H / 128), 256, 0, stream>>>(
      Ax, W1B0, W1B1, b1, be1, spkbits1, flag1, cnt1);
  repair1_kernel<<<256, 256, 0, stream>>>(x, W1, b1, be1, flag1, cnt1, spkbits1);

  step2_kernel<<<dim3(B / 128, H2 / 128), 256, 0, stream>>>(
      spkbits1, W2h, W2l, b2, be2, spkbits2, flag2, cnt2);
  repair2_kernel<<<256, 256, 0, stream>>>(spkbits1, W2, b2, be2, flag2, cnt2, spkbits2);

  out_kernel<<<B / 4, 256, 0, stream>>>(spkbits2, Wo, bo, beo, out);
}

// Round 8
// 2712.393 us; speedup vs baseline: 3.1111x; 1.6594x over previous
//
#include <hip/hip_runtime.h>
#include <stdint.h>

// SpikingQNetwork B=16384 D=512 H=2048 H2=1024 A=8 T=8.
// Fast path: bf16 2-term-split MFMA GEMMs; near-threshold neurons repaired
// with f32 sequential-FMA (BLAS mimicry); spike bits patched via atomicXor.
// R7->R8: repair2 rework -- (1) MARGIN2 5e-4 (layer-2 flags ~4x fewer; still
// ~10x over deviation tail), (2) predicated fixed-loop sum (RN-exact +0.0f)
// replacing serial ctz-walk: ILP-8 across timesteps, dense W2-row loads.

typedef __bf16 bf16;
typedef __attribute__((ext_vector_type(8))) __bf16 bf16x8;
typedef __attribute__((ext_vector_type(4))) float f32x4;

#define CAP1 2097152
#define CAP2 2097152
#define MARGIN 2e-3f     // layer 1
#define MARGIN2 5e-4f    // layer 2

__device__ __forceinline__ void gl16(const void* g, void* l) {
  __builtin_amdgcn_global_load_lds(
      (const __attribute__((address_space(1))) uint32_t*)g,
      (__attribute__((address_space(3))) uint32_t*)l, 16, 0, 0);
}

__device__ __forceinline__ float clampf(float v) {
  return fminf(fmaxf(v, 0.f), 1.f);
}

__device__ __forceinline__ uint32_t expand2(uint32_t b) {
  // 2 spike bits -> 2 packed bf16 (1.0 = 0x3F80)
  return ((b & 1u) ? 0x3F80u : 0u) | ((b & 2u) ? 0x3F800000u : 0u);
}

// ---------------- splits (bf16 hi/lo) -------------------------------------

__global__ void split_x_kernel(const float* __restrict__ x, bf16* __restrict__ Ax) {
  int i = blockIdx.x * 256 + threadIdx.x;   // B*D
  int b = i >> 9, d = i & 511;
  float v = x[i];
  bf16 hi = (bf16)v;
  bf16 lo = (bf16)(v - (float)hi);
  size_t base = (size_t)b * 1024;
  Ax[base + d] = hi;
  Ax[base + 512 + d] = lo;
}

__global__ void split_w1_kernel(const float* __restrict__ W1, bf16* __restrict__ B0,
                                bf16* __restrict__ B1) {
  int i = blockIdx.x * 256 + threadIdx.x;   // H*D
  int r = i >> 9, d = i & 511;
  float v = W1[i];
  bf16 hi = (bf16)v;
  bf16 lo = (bf16)(v - (float)hi);
  size_t base = (size_t)r * 1024;
  B0[base + d] = hi;  B0[base + 512 + d] = lo;   // [w0|w1]
  B1[base + d] = lo;  B1[base + 512 + d] = hi;   // [w1|w0]
}

__global__ void split_w2_kernel(const float* __restrict__ W2, bf16* __restrict__ Wh,
                                bf16* __restrict__ Wl) {
  int i = blockIdx.x * 256 + threadIdx.x;   // H2*H
  float v = W2[i];
  bf16 hi = (bf16)v;
  Wh[i] = hi;
  Wl[i] = (bf16)(v - (float)hi);
}

// -------- GEMM1 + fused LIF1 (ballot-packed, hierarchical flags) ----------

#define SA_OFF  0
#define SB0_OFF 16384
#define SB1_OFF 32768

__global__ __launch_bounds__(256, 2) void gemm1_lif1_kernel(
    const bf16* __restrict__ A, const bf16* __restrict__ B0,
    const bf16* __restrict__ B1, const float* __restrict__ bias,
    const float* __restrict__ beta1p,
    uint32_t* __restrict__ spkbits1, uint2* __restrict__ flag1,
    uint32_t* __restrict__ cnt1)
{
  __shared__ __align__(16) uint8_t lds[49152];
  const int tid = threadIdx.x;
  const int lane = tid & 63;
  const int wave = tid >> 6;
  const int wm = (wave >> 1) * 64, wn = (wave & 1) * 64;
  const size_t brow = (size_t)blockIdx.x * 128;
  const size_t bcol = (size_t)blockIdx.y * 128;
  const int K = 1024;
  const float be = clampf(beta1p[0]);

  const bf16* gA  = A  + brow * K;
  const bf16* gB0 = B0 + bcol * K;
  const bf16* gB1 = B1 + bcol * K;

  f32x4 acc[4][4] = {};

  for (int kk = 0; kk < K; kk += 64) {
#pragma unroll
    for (int q = 0; q < 4; ++q) {
      const int flat = q * 256 + tid;
      const int row = flat >> 3;
      const int s   = flat & 7;
      const int c8  = (s ^ (row & 7)) * 8;   // pre-swizzled source column
      gl16(gA  + (size_t)row * K + kk + c8, lds + SA_OFF  + flat * 16);
      gl16(gB0 + (size_t)row * K + kk + c8, lds + SB0_OFF + flat * 16);
      gl16(gB1 + (size_t)row * K + kk + c8, lds + SB1_OFF + flat * 16);
    }
    asm volatile("s_waitcnt vmcnt(0)" ::: "memory");
    __syncthreads();
#pragma unroll
    for (int ks = 0; ks < 2; ++ks) {
      bf16x8 af[4], b0f[4], b1f[4];
#pragma unroll
      for (int i = 0; i < 4; ++i) {
        const int ra = wm + i * 16 + (lane & 15);
        const int sa = ((ks * 4 + (lane >> 4)) ^ (ra & 7)) * 16;
        af[i]  = *(const bf16x8*)(lds + SA_OFF  + ra * 128 + sa);
        const int rb = wn + i * 16 + (lane & 15);
        const int sb = ((ks * 4 + (lane >> 4)) ^ (rb & 7)) * 16;
        b0f[i] = *(const bf16x8*)(lds + SB0_OFF + rb * 128 + sb);
        b1f[i] = *(const bf16x8*)(lds + SB1_OFF + rb * 128 + sb);
      }
#pragma unroll
      for (int m = 0; m < 4; ++m)
#pragma unroll
        for (int n = 0; n < 4; ++n) {
          acc[m][n] = __builtin_amdgcn_mfma_f32_16x16x32_bf16(af[m], b0f[n], acc[m][n], 0, 0, 0);
          acc[m][n] = __builtin_amdgcn_mfma_f32_16x16x32_bf16(af[m], b1f[n], acc[m][n], 0, 0, 0);
        }
    }
    __syncthreads();
  }

  // LDS reuse: flag list (tiles dead after K-loop's final barrier)
  uint32_t* lcnt  = (uint32_t*)lds;            // [0]
  uint32_t* lbase = (uint32_t*)(lds + 4);      // [1]
  uint2*    llist = (uint2*)(lds + 16);
  const uint32_t CAPL = 3000;
  if (tid == 0) *lcnt = 0;
  __syncthreads();

  // LIF1: element-outer (1 mem/hist live), ballot-packed bit output
  const int rg = lane >> 4;
  const bool writer = (lane & 15) == 0;
  uint16_t* sp16 = (uint16_t*)spkbits1;

#pragma unroll
  for (int m = 0; m < 4; ++m)
#pragma unroll
    for (int n = 0; n < 4; ++n) {
      const int chb = (int)(bcol) + wn + n * 16;   // wave-uniform col base
      const int w32 = chb >> 5, half = (chb >> 4) & 1;
      const float bv = bias[chb + (lane & 15)];
#pragma unroll
      for (int j = 0; j < 4; ++j) {
        const float c = acc[m][n][j] + bv;
        float mem = 0.f; uint32_t hist = 0; bool nearThr = false;
#pragma unroll
        for (int t = 0; t < 8; ++t) {
          float rst = (mem > 1.f) ? 1.f : 0.f;
          mem = be * mem + c - rst;
          uint32_t bit = (mem > 1.f) ? 1u : 0u;
          hist |= bit << t;
          nearThr |= (fabsf(mem - 1.f) < MARGIN);
        }
#pragma unroll
        for (int t = 0; t < 8; ++t) {
          unsigned long long bal = __ballot((hist >> t) & 1u);
          if (writer) {
            uint32_t row = (uint32_t)(brow + wm + m * 16 + rg * 4 + j);
            size_t idx = ((size_t)(t * 64 + w32) * 16384 + row) * 2 + half;
            sp16[idx] = (uint16_t)(bal >> (rg * 16));
          }
        }
        if (nearThr) {
          const uint32_t h = (uint32_t)(chb + (lane & 15));
          const uint32_t b = (uint32_t)(brow + wm + m * 16 + rg * 4 + j);
          uint2 en; en.x = (h << 14) | b; en.y = hist;
          uint32_t pos = atomicAdd(lcnt, 1u);
          if (pos < CAPL) llist[pos] = en;
          else { uint32_t g = atomicAdd(cnt1, 1u); if (g < CAP1) flag1[g] = en; }
        }
      }
    }

  __syncthreads();
  uint32_t ln = *lcnt; if (ln > CAPL) ln = CAPL;
  if (tid == 0) *lbase = atomicAdd(cnt1, ln);
  __syncthreads();
  const uint32_t gb = *lbase;
  for (uint32_t i = tid; i < ln; i += 256) {
    uint32_t g = gb + i;
    if (g < CAP1) flag1[g] = llist[i];
  }
}

// ------- repair1: f32 sequential-FMA (BLAS-order mimicry) redo -------------

__global__ __launch_bounds__(256) void repair1_kernel(
    const float* __restrict__ x, const float* __restrict__ W1,
    const float* __restrict__ b1, const float* __restrict__ beta1p,
    const uint2* __restrict__ flag1, const uint32_t* __restrict__ cnt1,
    uint32_t* __restrict__ spkbits1)
{
  uint32_t n = cnt1[0]; if (n > CAP1) n = CAP1;
  const float be = clampf(beta1p[0]);
  for (uint32_t i = blockIdx.x * 256 + threadIdx.x; i < n; i += gridDim.x * 256) {
    uint2 e = flag1[i];
    int h = e.x >> 14, b = e.x & 16383;
    const float* xr = x + (size_t)b * 512;
    const float* wr = W1 + (size_t)h * 512;
    float s = 0.f;                       // sgemm: sequential ascending-k FMA
    for (int d = 0; d < 512; ++d) s = fmaf(xr[d], wr[d], s);
    s = __fadd_rn(s, b1[h]);
    float m = 0.f; uint32_t eb = 0;
#pragma unroll
    for (int t = 0; t < 8; ++t) {
      float rst = (__fsub_rn(m, 1.f) > 0.f) ? 1.f : 0.f;
      m = __fsub_rn(__fadd_rn(__fmul_rn(be, m), s), rst);
      if (__fsub_rn(m, 1.f) > 0.f) eb |= 1u << t;
    }
    uint32_t diff = eb ^ (e.y & 0xFFu);
    if (diff) {
#pragma unroll
      for (int t = 0; t < 8; ++t)
        if ((diff >> t) & 1u)
          atomicXor(&spkbits1[((size_t)t * 64 + (h >> 5)) * 16384 + b], 1u << (h & 31));
    }
  }
}

// ------- step2: fused per-t GEMM + LIF2 (ballot-packed, hier flags) --------

__global__ __launch_bounds__(256, 2) void step2_kernel(
    const uint32_t* __restrict__ spkbits1,
    const bf16* __restrict__ W2h, const bf16* __restrict__ W2l,
    const float* __restrict__ b2, const float* __restrict__ beta2p,
    uint32_t* __restrict__ spkbits2, uint32_t* __restrict__ flag2,
    uint32_t* __restrict__ cnt2)
{
  __shared__ __align__(16) uint8_t lds[49152];
  const int K = 2048;
  const int tid = threadIdx.x;
  const int lane = tid & 63;
  const int wave = tid >> 6;
  const int wm = (wave >> 1) * 64, wn = (wave & 1) * 64;
  const size_t brow = (size_t)blockIdx.x * 128;
  const size_t bcol = (size_t)blockIdx.y * 128;
  const float be2 = clampf(beta2p[0]);

  const bf16* gB0 = W2h + bcol * K;
  const bf16* gB1 = W2l + bcol * K;

  float b2c[4];
#pragma unroll
  for (int n = 0; n < 4; ++n) b2c[n] = b2[bcol + wn + n * 16 + (lane & 15)];

  const int ar = tid & 127;
  const int aw = tid >> 7;
  const int rg = lane >> 4;
  const bool writer = (lane & 15) == 0;
  uint16_t* sp16 = (uint16_t*)spkbits2;

  f32x4 acc[4][4] = {};       // mem2, persistent across t
  unsigned long long flg = 0;

  for (int t = 0; t < 8; ++t) {
#pragma unroll
    for (int m = 0; m < 4; ++m)
#pragma unroll
      for (int n = 0; n < 4; ++n)
#pragma unroll
        for (int j = 0; j < 4; ++j) {
          float v = acc[m][n][j];
          float rst = (v > 1.f) ? 1.f : 0.f;
          acc[m][n][j] = be2 * v + (b2c[n] - rst);
        }

    for (int kk = 0; kk < K; kk += 64) {
      uint32_t bits = spkbits1[((size_t)t * 64 + (kk >> 5) + aw) * 16384 + brow + ar];
#pragma unroll
      for (int c = 0; c < 4; ++c) {
        uint4 u;
        u.x = expand2(bits >> (8 * c));
        u.y = expand2(bits >> (8 * c + 2));
        u.z = expand2(bits >> (8 * c + 4));
        u.w = expand2(bits >> (8 * c + 6));
        const int slot = (aw * 4 + c) ^ (ar & 7);
        *(uint4*)(lds + SA_OFF + ar * 128 + slot * 16) = u;
      }
#pragma unroll
      for (int q = 0; q < 4; ++q) {
        const int flat = q * 256 + tid;
        const int row = flat >> 3;
        const int s   = flat & 7;
        const int c8  = (s ^ (row & 7)) * 8;   // pre-swizzled source column
        gl16(gB0 + (size_t)row * K + kk + c8, lds + SB0_OFF + flat * 16);
        gl16(gB1 + (size_t)row * K + kk + c8, lds + SB1_OFF + flat * 16);
      }
      asm volatile("s_waitcnt vmcnt(0)" ::: "memory");
      __syncthreads();
#pragma unroll
      for (int ks = 0; ks < 2; ++ks) {
        bf16x8 af[4], b0f[4], b1f[4];
#pragma unroll
        for (int i = 0; i < 4; ++i) {
          const int ra = wm + i * 16 + (lane & 15);
          const int sa = ((ks * 4 + (lane >> 4)) ^ (ra & 7)) * 16;
          af[i] = *(const bf16x8*)(lds + SA_OFF + ra * 128 + sa);
          const int rb = wn + i * 16 + (lane & 15);
          const int sb = ((ks * 4 + (lane >> 4)) ^ (rb & 7)) * 16;
          b0f[i] = *(const bf16x8*)(lds + SB0_OFF + rb * 128 + sb);
          b1f[i] = *(const bf16x8*)(lds + SB1_OFF + rb * 128 + sb);
        }
#pragma unroll
        for (int m = 0; m < 4; ++m)
#pragma unroll
          for (int n = 0; n < 4; ++n) {
            acc[m][n] = __builtin_amdgcn_mfma_f32_16x16x32_bf16(af[m], b0f[n], acc[m][n], 0, 0, 0);
            acc[m][n] = __builtin_amdgcn_mfma_f32_16x16x32_bf16(af[m], b1f[n], acc[m][n], 0, 0, 0);
          }
      }
      __syncthreads();
    }

    // spike bits via ballot (register-only; no barriers)
#pragma unroll
    for (int m = 0; m < 4; ++m)
#pragma unroll
      for (int n = 0; n < 4; ++n) {
        const int chb = (int)(bcol) + wn + n * 16;
        const int w32 = chb >> 5, half = (chb >> 4) & 1;
#pragma unroll
        for (int j = 0; j < 4; ++j) {
          float v = acc[m][n][j];
          if (fabsf(v - 1.f) < MARGIN2) flg |= 1ull << (m * 16 + n * 4 + j);
          unsigned long long bal = __ballot(v > 1.f);
          if (writer) {
            uint32_t row = (uint32_t)(brow + wm + m * 16 + rg * 4 + j);
            size_t idx = ((size_t)(t * 32 + w32) * 16384 + row) * 2 + half;
            sp16[idx] = (uint16_t)(bal >> (rg * 16));
          }
        }
      }
  }

  // hierarchical flag collection (LDS tiles dead)
  uint32_t* lcnt  = (uint32_t*)lds;
  uint32_t* lbase = (uint32_t*)(lds + 4);
  uint32_t* llist = (uint32_t*)(lds + 16);
  const uint32_t CAPL = 6000;
  if (tid == 0) *lcnt = 0;
  __syncthreads();

  if (flg) {
#pragma unroll
    for (int m = 0; m < 4; ++m)
#pragma unroll
      for (int n = 0; n < 4; ++n)
#pragma unroll
        for (int j = 0; j < 4; ++j)
          if ((flg >> (m * 16 + n * 4 + j)) & 1ull) {
            const int row = wm + m * 16 + rg * 4 + j;
            const int col = wn + n * 16 + (lane & 15);
            uint32_t en = (uint32_t)(((brow + row) << 10) | (bcol + col));
            uint32_t pos = atomicAdd(lcnt, 1u);
            if (pos < CAPL) llist[pos] = en;
            else { uint32_t g = atomicAdd(cnt2, 1u); if (g < CAP2) flag2[g] = en; }
          }
  }

  __syncthreads();
  uint32_t ln = *lcnt; if (ln > CAPL) ln = CAPL;
  if (tid == 0) *lbase = atomicAdd(cnt2, ln);
  __syncthreads();
  const uint32_t gb = *lbase;
  for (uint32_t i = tid; i < ln; i += 256) {
    uint32_t g = gb + i;
    if (g < CAP2) flag2[g] = llist[i];
  }
}

// ------- repair2: f32 sequential-sum mimicry, ILP-8 predicated loop --------

__global__ __launch_bounds__(256) void repair2_kernel(
    const uint32_t* __restrict__ spkbits1, const float* __restrict__ W2,
    const float* __restrict__ b2, const float* __restrict__ beta2p,
    const uint32_t* __restrict__ flag2, const uint32_t* __restrict__ cnt2,
    uint32_t* __restrict__ spkbits2)
{
  uint32_t n = cnt2[0]; if (n > CAP2) n = CAP2;
  const float be = clampf(beta2p[0]);
  for (uint32_t i = blockIdx.x * 256 + threadIdx.x; i < n; i += gridDim.x * 256) {
    uint32_t e = flag2[i];
    int b = e >> 10, h2 = e & 1023;
    const float* wr = W2 + (size_t)h2 * 2048;
    const float bias = b2[h2];
    float s[8] = {0, 0, 0, 0, 0, 0, 0, 0};
    for (int w = 0; w < 64; ++w) {
      uint32_t bt[8];
#pragma unroll
      for (int t = 0; t < 8; ++t)
        bt[t] = spkbits1[((size_t)t * 64 + w) * 16384 + b];
      // predicated adds: +0.0f is RN-exact (only -0 -> +0, harmless), so the
      // ascending-k sequential order of each t-chain is bit-preserved; the 8
      // chains are independent -> ILP hides add/load latency.
#pragma unroll 8
      for (int k = 0; k < 32; ++k) {
        const float wv = wr[w * 32 + k];
#pragma unroll
        for (int t = 0; t < 8; ++t) {
          float addend = ((bt[t] >> k) & 1u) ? wv : 0.0f;
          s[t] = __fadd_rn(s[t], addend);
        }
      }
    }
    float m = 0.f;
#pragma unroll
    for (int t = 0; t < 8; ++t) {
      float st = __fadd_rn(s[t], bias);
      float rst = (__fsub_rn(m, 1.f) > 0.f) ? 1.f : 0.f;
      m = __fsub_rn(__fadd_rn(__fmul_rn(be, m), st), rst);
      uint32_t exact = (__fsub_rn(m, 1.f) > 0.f) ? 1u : 0u;
      uint32_t* wp = &spkbits2[((size_t)t * 32 + (h2 >> 5)) * 16384 + b];
      uint32_t stored = (*wp >> (h2 & 31)) & 1u;
      if (stored != exact) atomicXor(wp, 1u << (h2 & 31));
    }
  }
}

// ---------------- output: f64 mem_out recurrence + max from spike bits -----

__global__ __launch_bounds__(256) void out_kernel(
    const uint32_t* __restrict__ spkbits2, const float* __restrict__ Wo,
    const float* __restrict__ bo, const float* __restrict__ betaop,
    float* __restrict__ out)
{
  const int wave = threadIdx.x >> 6, lane = threadIdx.x & 63;
  const int b = blockIdx.x * 4 + wave;
  const double beo = (double)clampf(betaop[0]);
  const int wrd = lane >> 1;
  const int half = lane & 1;
  const int h2base = lane * 16;
  double mo[8] = {0, 0, 0, 0, 0, 0, 0, 0};
  double mx[8];
#pragma unroll
  for (int a = 0; a < 8; ++a) mx[a] = -1e9;
  for (int t = 0; t < 8; ++t) {
    uint32_t word = spkbits2[((size_t)t * 32 + wrd) * 16384 + b];
    uint32_t bits = (word >> (half * 16)) & 0xFFFFu;
    double s[8] = {0, 0, 0, 0, 0, 0, 0, 0};
#pragma unroll
    for (int k = 0; k < 16; ++k) {
      if ((bits >> k) & 1u) {
#pragma unroll
        for (int a = 0; a < 8; ++a)
          s[a] += (double)Wo[a * 1024 + h2base + k];
      }
    }
#pragma unroll
    for (int a = 0; a < 8; ++a)
#pragma unroll
      for (int off = 32; off > 0; off >>= 1)
        s[a] += __shfl_down(s[a], off, 64);
    if (lane == 0) {
#pragma unroll
      for (int a = 0; a < 8; ++a) {
        mo[a] = beo * mo[a] + (s[a] + (double)bo[a]);
        mx[a] = fmax(mx[a], mo[a]);
      }
    }
  }
  if (lane == 0) {
#pragma unroll
    for (int a = 0; a < 8; ++a)
      out[(size_t)b * 8 + a] = (float)mx[a];
  }
}

__global__ void zero_hdr_kernel(uint32_t* p) {
  if (threadIdx.x < 64) p[threadIdx.x] = 0;
}

__global__ void fill_sentinel(float* out, int n, float v) {
  int i = blockIdx.x * 256 + threadIdx.x;
  if (i < n) out[i] = v;
}

// ---------------- launch ----------------

extern "C" void kernel_launch(void* const* d_in, const int* in_sizes, int n_in,
                              void* d_out, int out_size, void* d_ws, size_t ws_size,
                              hipStream_t stream)
{
  (void)in_sizes; (void)n_in;
  const float* x   = (const float*)d_in[0];
  const float* W1  = (const float*)d_in[1];
  const float* b1  = (const float*)d_in[2];
  const float* W2  = (const float*)d_in[3];
  const float* b2  = (const float*)d_in[4];
  const float* Wo  = (const float*)d_in[5];
  const float* bo  = (const float*)d_in[6];
  const float* be1 = (const float*)d_in[7];
  const float* be2 = (const float*)d_in[8];
  const float* beo = (const float*)d_in[9];
  float* out = (float*)d_out;

  const int B = 16384, D = 512, H = 2048, H2 = 1024;

  const size_t sz_hdr  = 256;
  const size_t sz_Ax   = (size_t)B * 1024 * 2;        // 32 MB
  const size_t sz_W1s  = (size_t)H * 1024 * 2;        // 4 MB each
  const size_t sz_W2s  = (size_t)H2 * H * 2;          // 4 MB each
  const size_t sz_b1   = (size_t)8 * 64 * B * 4;      // 32 MB
  const size_t sz_b2   = (size_t)8 * 32 * B * 4;      // 16 MB
  const size_t sz_f1   = (size_t)CAP1 * 8;            // 16 MB
  const size_t sz_f2   = (size_t)CAP2 * 4;            // 8 MB
  const size_t need = sz_hdr + sz_Ax + 2 * sz_W1s + 2 * sz_W2s +
                      sz_b1 + sz_b2 + sz_f1 + sz_f2;  // ~120 MB

  if (ws_size < need) {
    fill_sentinel<<<(out_size + 255) / 256, 256, 0, stream>>>(
        out, out_size, 1000.0f + (float)(ws_size >> 20));
    return;
  }

  uint8_t* p = (uint8_t*)d_ws;
  uint32_t* hdr = (uint32_t*)p;     p += sz_hdr;
  bf16* Ax      = (bf16*)p;         p += sz_Ax;
  bf16* W1B0    = (bf16*)p;         p += sz_W1s;
  bf16* W1B1    = (bf16*)p;         p += sz_W1s;
  bf16* W2h     = (bf16*)p;         p += sz_W2s;
  bf16* W2l     = (bf16*)p;         p += sz_W2s;
  uint32_t* spkbits1 = (uint32_t*)p; p += sz_b1;
  uint32_t* spkbits2 = (uint32_t*)p; p += sz_b2;
  uint2* flag1  = (uint2*)p;        p += sz_f1;
  uint32_t* flag2 = (uint32_t*)p;   p += sz_f2;
  uint32_t* cnt1 = hdr + 0;
  uint32_t* cnt2 = hdr + 1;

  zero_hdr_kernel<<<1, 64, 0, stream>>>(hdr);
  split_x_kernel <<<(B * D) / 256, 256, 0, stream>>>(x, Ax);
  split_w1_kernel<<<(H * D) / 256, 256, 0, stream>>>(W1, W1B0, W1B1);
  split_w2_kernel<<<(H2 * H) / 256, 256, 0, stream>>>(W2, W2h, W2l);

  gemm1_lif1_kernel<<<dim3(B / 128, H / 128), 256, 0, stream>>>(
      Ax, W1B0, W1B1, b1, be1, spkbits1, flag1, cnt1);
  repair1_kernel<<<256, 256, 0, stream>>>(x, W1, b1, be1, flag1, cnt1, spkbits1);

  step2_kernel<<<dim3(B / 128, H2 / 128), 256, 0, stream>>>(
      spkbits1, W2h, W2l, b2, be2, spkbits2, flag2, cnt2);
  repair2_kernel<<<256, 256, 0, stream>>>(spkbits1, W2, b2, be2, flag2, cnt2, spkbits2);

  out_kernel<<<B / 4, 256, 0, stream>>>(spkbits2, Wo, bo, beo, out);
}

// Round 9
// 1802.819 us; speedup vs baseline: 4.6808x; 1.5045x over previous
//
#include <hip/hip_runtime.h>
#include <stdint.h>

// SpikingQNetwork B=16384 D=512 H=2048 H2=1024 A=8 T=8.
// Fast path: bf16 2-term-split MFMA GEMMs; near-threshold neurons repaired
// with f32 sequential-FMA (BLAS mimicry); spike bits patched via atomicXor.
// R8->R9: out_kernel rewritten f64->f32 with (a,slice) lane split:
// predicated slice sums (ILP-8 over t), 3-level shfl reduce, f32 recurrence.
// (np reference is f32 end-to-end; nothing thresholds mem_out downstream.)

typedef __bf16 bf16;
typedef __attribute__((ext_vector_type(8))) __bf16 bf16x8;
typedef __attribute__((ext_vector_type(4))) float f32x4;

#define CAP1 2097152
#define CAP2 2097152
#define MARGIN 2e-3f     // layer 1
#define MARGIN2 5e-4f    // layer 2

__device__ __forceinline__ void gl16(const void* g, void* l) {
  __builtin_amdgcn_global_load_lds(
      (const __attribute__((address_space(1))) uint32_t*)g,
      (__attribute__((address_space(3))) uint32_t*)l, 16, 0, 0);
}

__device__ __forceinline__ float clampf(float v) {
  return fminf(fmaxf(v, 0.f), 1.f);
}

__device__ __forceinline__ uint32_t expand2(uint32_t b) {
  // 2 spike bits -> 2 packed bf16 (1.0 = 0x3F80)
  return ((b & 1u) ? 0x3F80u : 0u) | ((b & 2u) ? 0x3F800000u : 0u);
}

// ---------------- splits (bf16 hi/lo) -------------------------------------

__global__ void split_x_kernel(const float* __restrict__ x, bf16* __restrict__ Ax) {
  int i = blockIdx.x * 256 + threadIdx.x;   // B*D
  int b = i >> 9, d = i & 511;
  float v = x[i];
  bf16 hi = (bf16)v;
  bf16 lo = (bf16)(v - (float)hi);
  size_t base = (size_t)b * 1024;
  Ax[base + d] = hi;
  Ax[base + 512 + d] = lo;
}

__global__ void split_w1_kernel(const float* __restrict__ W1, bf16* __restrict__ B0,
                                bf16* __restrict__ B1) {
  int i = blockIdx.x * 256 + threadIdx.x;   // H*D
  int r = i >> 9, d = i & 511;
  float v = W1[i];
  bf16 hi = (bf16)v;
  bf16 lo = (bf16)(v - (float)hi);
  size_t base = (size_t)r * 1024;
  B0[base + d] = hi;  B0[base + 512 + d] = lo;   // [w0|w1]
  B1[base + d] = lo;  B1[base + 512 + d] = hi;   // [w1|w0]
}

__global__ void split_w2_kernel(const float* __restrict__ W2, bf16* __restrict__ Wh,
                                bf16* __restrict__ Wl) {
  int i = blockIdx.x * 256 + threadIdx.x;   // H2*H
  float v = W2[i];
  bf16 hi = (bf16)v;
  Wh[i] = hi;
  Wl[i] = (bf16)(v - (float)hi);
}

// -------- GEMM1 + fused LIF1 (ballot-packed, hierarchical flags) ----------

#define SA_OFF  0
#define SB0_OFF 16384
#define SB1_OFF 32768

__global__ __launch_bounds__(256, 2) void gemm1_lif1_kernel(
    const bf16* __restrict__ A, const bf16* __restrict__ B0,
    const bf16* __restrict__ B1, const float* __restrict__ bias,
    const float* __restrict__ beta1p,
    uint32_t* __restrict__ spkbits1, uint2* __restrict__ flag1,
    uint32_t* __restrict__ cnt1)
{
  __shared__ __align__(16) uint8_t lds[49152];
  const int tid = threadIdx.x;
  const int lane = tid & 63;
  const int wave = tid >> 6;
  const int wm = (wave >> 1) * 64, wn = (wave & 1) * 64;
  const size_t brow = (size_t)blockIdx.x * 128;
  const size_t bcol = (size_t)blockIdx.y * 128;
  const int K = 1024;
  const float be = clampf(beta1p[0]);

  const bf16* gA  = A  + brow * K;
  const bf16* gB0 = B0 + bcol * K;
  const bf16* gB1 = B1 + bcol * K;

  f32x4 acc[4][4] = {};

  for (int kk = 0; kk < K; kk += 64) {
#pragma unroll
    for (int q = 0; q < 4; ++q) {
      const int flat = q * 256 + tid;
      const int row = flat >> 3;
      const int s   = flat & 7;
      const int c8  = (s ^ (row & 7)) * 8;   // pre-swizzled source column
      gl16(gA  + (size_t)row * K + kk + c8, lds + SA_OFF  + flat * 16);
      gl16(gB0 + (size_t)row * K + kk + c8, lds + SB0_OFF + flat * 16);
      gl16(gB1 + (size_t)row * K + kk + c8, lds + SB1_OFF + flat * 16);
    }
    asm volatile("s_waitcnt vmcnt(0)" ::: "memory");
    __syncthreads();
#pragma unroll
    for (int ks = 0; ks < 2; ++ks) {
      bf16x8 af[4], b0f[4], b1f[4];
#pragma unroll
      for (int i = 0; i < 4; ++i) {
        const int ra = wm + i * 16 + (lane & 15);
        const int sa = ((ks * 4 + (lane >> 4)) ^ (ra & 7)) * 16;
        af[i]  = *(const bf16x8*)(lds + SA_OFF  + ra * 128 + sa);
        const int rb = wn + i * 16 + (lane & 15);
        const int sb = ((ks * 4 + (lane >> 4)) ^ (rb & 7)) * 16;
        b0f[i] = *(const bf16x8*)(lds + SB0_OFF + rb * 128 + sb);
        b1f[i] = *(const bf16x8*)(lds + SB1_OFF + rb * 128 + sb);
      }
#pragma unroll
      for (int m = 0; m < 4; ++m)
#pragma unroll
        for (int n = 0; n < 4; ++n) {
          acc[m][n] = __builtin_amdgcn_mfma_f32_16x16x32_bf16(af[m], b0f[n], acc[m][n], 0, 0, 0);
          acc[m][n] = __builtin_amdgcn_mfma_f32_16x16x32_bf16(af[m], b1f[n], acc[m][n], 0, 0, 0);
        }
    }
    __syncthreads();
  }

  // LDS reuse: flag list (tiles dead after K-loop's final barrier)
  uint32_t* lcnt  = (uint32_t*)lds;            // [0]
  uint32_t* lbase = (uint32_t*)(lds + 4);      // [1]
  uint2*    llist = (uint2*)(lds + 16);
  const uint32_t CAPL = 3000;
  if (tid == 0) *lcnt = 0;
  __syncthreads();

  // LIF1: element-outer (1 mem/hist live), ballot-packed bit output
  const int rg = lane >> 4;
  const bool writer = (lane & 15) == 0;
  uint16_t* sp16 = (uint16_t*)spkbits1;

#pragma unroll
  for (int m = 0; m < 4; ++m)
#pragma unroll
    for (int n = 0; n < 4; ++n) {
      const int chb = (int)(bcol) + wn + n * 16;   // wave-uniform col base
      const int w32 = chb >> 5, half = (chb >> 4) & 1;
      const float bv = bias[chb + (lane & 15)];
#pragma unroll
      for (int j = 0; j < 4; ++j) {
        const float c = acc[m][n][j] + bv;
        float mem = 0.f; uint32_t hist = 0; bool nearThr = false;
#pragma unroll
        for (int t = 0; t < 8; ++t) {
          float rst = (mem > 1.f) ? 1.f : 0.f;
          mem = be * mem + c - rst;
          uint32_t bit = (mem > 1.f) ? 1u : 0u;
          hist |= bit << t;
          nearThr |= (fabsf(mem - 1.f) < MARGIN);
        }
#pragma unroll
        for (int t = 0; t < 8; ++t) {
          unsigned long long bal = __ballot((hist >> t) & 1u);
          if (writer) {
            uint32_t row = (uint32_t)(brow + wm + m * 16 + rg * 4 + j);
            size_t idx = ((size_t)(t * 64 + w32) * 16384 + row) * 2 + half;
            sp16[idx] = (uint16_t)(bal >> (rg * 16));
          }
        }
        if (nearThr) {
          const uint32_t h = (uint32_t)(chb + (lane & 15));
          const uint32_t b = (uint32_t)(brow + wm + m * 16 + rg * 4 + j);
          uint2 en; en.x = (h << 14) | b; en.y = hist;
          uint32_t pos = atomicAdd(lcnt, 1u);
          if (pos < CAPL) llist[pos] = en;
          else { uint32_t g = atomicAdd(cnt1, 1u); if (g < CAP1) flag1[g] = en; }
        }
      }
    }

  __syncthreads();
  uint32_t ln = *lcnt; if (ln > CAPL) ln = CAPL;
  if (tid == 0) *lbase = atomicAdd(cnt1, ln);
  __syncthreads();
  const uint32_t gb = *lbase;
  for (uint32_t i = tid; i < ln; i += 256) {
    uint32_t g = gb + i;
    if (g < CAP1) flag1[g] = llist[i];
  }
}

// ------- repair1: f32 sequential-FMA (BLAS-order mimicry) redo -------------

__global__ __launch_bounds__(256) void repair1_kernel(
    const float* __restrict__ x, const float* __restrict__ W1,
    const float* __restrict__ b1, const float* __restrict__ beta1p,
    const uint2* __restrict__ flag1, const uint32_t* __restrict__ cnt1,
    uint32_t* __restrict__ spkbits1)
{
  uint32_t n = cnt1[0]; if (n > CAP1) n = CAP1;
  const float be = clampf(beta1p[0]);
  for (uint32_t i = blockIdx.x * 256 + threadIdx.x; i < n; i += gridDim.x * 256) {
    uint2 e = flag1[i];
    int h = e.x >> 14, b = e.x & 16383;
    const float* xr = x + (size_t)b * 512;
    const float* wr = W1 + (size_t)h * 512;
    float s = 0.f;                       // sgemm: sequential ascending-k FMA
    for (int d = 0; d < 512; ++d) s = fmaf(xr[d], wr[d], s);
    s = __fadd_rn(s, b1[h]);
    float m = 0.f; uint32_t eb = 0;
#pragma unroll
    for (int t = 0; t < 8; ++t) {
      float rst = (__fsub_rn(m, 1.f) > 0.f) ? 1.f : 0.f;
      m = __fsub_rn(__fadd_rn(__fmul_rn(be, m), s), rst);
      if (__fsub_rn(m, 1.f) > 0.f) eb |= 1u << t;
    }
    uint32_t diff = eb ^ (e.y & 0xFFu);
    if (diff) {
#pragma unroll
      for (int t = 0; t < 8; ++t)
        if ((diff >> t) & 1u)
          atomicXor(&spkbits1[((size_t)t * 64 + (h >> 5)) * 16384 + b], 1u << (h & 31));
    }
  }
}

// ------- step2: fused per-t GEMM + LIF2 (ballot-packed, hier flags) --------

__global__ __launch_bounds__(256, 2) void step2_kernel(
    const uint32_t* __restrict__ spkbits1,
    const bf16* __restrict__ W2h, const bf16* __restrict__ W2l,
    const float* __restrict__ b2, const float* __restrict__ beta2p,
    uint32_t* __restrict__ spkbits2, uint32_t* __restrict__ flag2,
    uint32_t* __restrict__ cnt2)
{
  __shared__ __align__(16) uint8_t lds[49152];
  const int K = 2048;
  const int tid = threadIdx.x;
  const int lane = tid & 63;
  const int wave = tid >> 6;
  const int wm = (wave >> 1) * 64, wn = (wave & 1) * 64;
  const size_t brow = (size_t)blockIdx.x * 128;
  const size_t bcol = (size_t)blockIdx.y * 128;
  const float be2 = clampf(beta2p[0]);

  const bf16* gB0 = W2h + bcol * K;
  const bf16* gB1 = W2l + bcol * K;

  float b2c[4];
#pragma unroll
  for (int n = 0; n < 4; ++n) b2c[n] = b2[bcol + wn + n * 16 + (lane & 15)];

  const int ar = tid & 127;
  const int aw = tid >> 7;
  const int rg = lane >> 4;
  const bool writer = (lane & 15) == 0;
  uint16_t* sp16 = (uint16_t*)spkbits2;

  f32x4 acc[4][4] = {};       // mem2, persistent across t
  unsigned long long flg = 0;

  for (int t = 0; t < 8; ++t) {
#pragma unroll
    for (int m = 0; m < 4; ++m)
#pragma unroll
      for (int n = 0; n < 4; ++n)
#pragma unroll
        for (int j = 0; j < 4; ++j) {
          float v = acc[m][n][j];
          float rst = (v > 1.f) ? 1.f : 0.f;
          acc[m][n][j] = be2 * v + (b2c[n] - rst);
        }

    for (int kk = 0; kk < K; kk += 64) {
      uint32_t bits = spkbits1[((size_t)t * 64 + (kk >> 5) + aw) * 16384 + brow + ar];
#pragma unroll
      for (int c = 0; c < 4; ++c) {
        uint4 u;
        u.x = expand2(bits >> (8 * c));
        u.y = expand2(bits >> (8 * c + 2));
        u.z = expand2(bits >> (8 * c + 4));
        u.w = expand2(bits >> (8 * c + 6));
        const int slot = (aw * 4 + c) ^ (ar & 7);
        *(uint4*)(lds + SA_OFF + ar * 128 + slot * 16) = u;
      }
#pragma unroll
      for (int q = 0; q < 4; ++q) {
        const int flat = q * 256 + tid;
        const int row = flat >> 3;
        const int s   = flat & 7;
        const int c8  = (s ^ (row & 7)) * 8;   // pre-swizzled source column
        gl16(gB0 + (size_t)row * K + kk + c8, lds + SB0_OFF + flat * 16);
        gl16(gB1 + (size_t)row * K + kk + c8, lds + SB1_OFF + flat * 16);
      }
      asm volatile("s_waitcnt vmcnt(0)" ::: "memory");
      __syncthreads();
#pragma unroll
      for (int ks = 0; ks < 2; ++ks) {
        bf16x8 af[4], b0f[4], b1f[4];
#pragma unroll
        for (int i = 0; i < 4; ++i) {
          const int ra = wm + i * 16 + (lane & 15);
          const int sa = ((ks * 4 + (lane >> 4)) ^ (ra & 7)) * 16;
          af[i] = *(const bf16x8*)(lds + SA_OFF + ra * 128 + sa);
          const int rb = wn + i * 16 + (lane & 15);
          const int sb = ((ks * 4 + (lane >> 4)) ^ (rb & 7)) * 16;
          b0f[i] = *(const bf16x8*)(lds + SB0_OFF + rb * 128 + sb);
          b1f[i] = *(const bf16x8*)(lds + SB1_OFF + rb * 128 + sb);
        }
#pragma unroll
        for (int m = 0; m < 4; ++m)
#pragma unroll
          for (int n = 0; n < 4; ++n) {
            acc[m][n] = __builtin_amdgcn_mfma_f32_16x16x32_bf16(af[m], b0f[n], acc[m][n], 0, 0, 0);
            acc[m][n] = __builtin_amdgcn_mfma_f32_16x16x32_bf16(af[m], b1f[n], acc[m][n], 0, 0, 0);
          }
      }
      __syncthreads();
    }

    // spike bits via ballot (register-only; no barriers)
#pragma unroll
    for (int m = 0; m < 4; ++m)
#pragma unroll
      for (int n = 0; n < 4; ++n) {
        const int chb = (int)(bcol) + wn + n * 16;
        const int w32 = chb >> 5, half = (chb >> 4) & 1;
#pragma unroll
        for (int j = 0; j < 4; ++j) {
          float v = acc[m][n][j];
          if (fabsf(v - 1.f) < MARGIN2) flg |= 1ull << (m * 16 + n * 4 + j);
          unsigned long long bal = __ballot(v > 1.f);
          if (writer) {
            uint32_t row = (uint32_t)(brow + wm + m * 16 + rg * 4 + j);
            size_t idx = ((size_t)(t * 32 + w32) * 16384 + row) * 2 + half;
            sp16[idx] = (uint16_t)(bal >> (rg * 16));
          }
        }
      }
  }

  // hierarchical flag collection (LDS tiles dead)
  uint32_t* lcnt  = (uint32_t*)lds;
  uint32_t* lbase = (uint32_t*)(lds + 4);
  uint32_t* llist = (uint32_t*)(lds + 16);
  const uint32_t CAPL = 6000;
  if (tid == 0) *lcnt = 0;
  __syncthreads();

  if (flg) {
#pragma unroll
    for (int m = 0; m < 4; ++m)
#pragma unroll
      for (int n = 0; n < 4; ++n)
#pragma unroll
        for (int j = 0; j < 4; ++j)
          if ((flg >> (m * 16 + n * 4 + j)) & 1ull) {
            const int row = wm + m * 16 + rg * 4 + j;
            const int col = wn + n * 16 + (lane & 15);
            uint32_t en = (uint32_t)(((brow + row) << 10) | (bcol + col));
            uint32_t pos = atomicAdd(lcnt, 1u);
            if (pos < CAPL) llist[pos] = en;
            else { uint32_t g = atomicAdd(cnt2, 1u); if (g < CAP2) flag2[g] = en; }
          }
  }

  __syncthreads();
  uint32_t ln = *lcnt; if (ln > CAPL) ln = CAPL;
  if (tid == 0) *lbase = atomicAdd(cnt2, ln);
  __syncthreads();
  const uint32_t gb = *lbase;
  for (uint32_t i = tid; i < ln; i += 256) {
    uint32_t g = gb + i;
    if (g < CAP2) flag2[g] = llist[i];
  }
}

// ------- repair2: f32 sequential-sum mimicry, ILP-8 predicated loop --------

__global__ __launch_bounds__(256) void repair2_kernel(
    const uint32_t* __restrict__ spkbits1, const float* __restrict__ W2,
    const float* __restrict__ b2, const float* __restrict__ beta2p,
    const uint32_t* __restrict__ flag2, const uint32_t* __restrict__ cnt2,
    uint32_t* __restrict__ spkbits2)
{
  uint32_t n = cnt2[0]; if (n > CAP2) n = CAP2;
  const float be = clampf(beta2p[0]);
  for (uint32_t i = blockIdx.x * 256 + threadIdx.x; i < n; i += gridDim.x * 256) {
    uint32_t e = flag2[i];
    int b = e >> 10, h2 = e & 1023;
    const float* wr = W2 + (size_t)h2 * 2048;
    const float bias = b2[h2];
    float s[8] = {0, 0, 0, 0, 0, 0, 0, 0};
    for (int w = 0; w < 64; ++w) {
      uint32_t bt[8];
#pragma unroll
      for (int t = 0; t < 8; ++t)
        bt[t] = spkbits1[((size_t)t * 64 + w) * 16384 + b];
      // predicated adds: +0.0f is RN-exact, ascending-k order bit-preserved;
      // 8 independent chains -> ILP hides add/load latency.
#pragma unroll 8
      for (int k = 0; k < 32; ++k) {
        const float wv = wr[w * 32 + k];
#pragma unroll
        for (int t = 0; t < 8; ++t) {
          float addend = ((bt[t] >> k) & 1u) ? wv : 0.0f;
          s[t] = __fadd_rn(s[t], addend);
        }
      }
    }
    float m = 0.f;
#pragma unroll
    for (int t = 0; t < 8; ++t) {
      float st = __fadd_rn(s[t], bias);
      float rst = (__fsub_rn(m, 1.f) > 0.f) ? 1.f : 0.f;
      m = __fsub_rn(__fadd_rn(__fmul_rn(be, m), st), rst);
      uint32_t exact = (__fsub_rn(m, 1.f) > 0.f) ? 1u : 0u;
      uint32_t* wp = &spkbits2[((size_t)t * 32 + (h2 >> 5)) * 16384 + b];
      uint32_t stored = (*wp >> (h2 & 31)) & 1u;
      if (stored != exact) atomicXor(wp, 1u << (h2 & 31));
    }
  }
}

// -------- output: f32 (a,slice) lane split + 3-level shfl reduce -----------

__global__ __launch_bounds__(256) void out_kernel(
    const uint32_t* __restrict__ spkbits2, const float* __restrict__ Wo,
    const float* __restrict__ bo, const float* __restrict__ betaop,
    float* __restrict__ out)
{
  const int wave = threadIdx.x >> 6, lane = threadIdx.x & 63;
  const int b = blockIdx.x * 4 + wave;
  const float beo = clampf(betaop[0]);
  const int a = lane & 7;        // output unit
  const int slice = lane >> 3;   // 128-wide h2 slice

  float s[8] = {0, 0, 0, 0, 0, 0, 0, 0};   // per-t partial sums
#pragma unroll
  for (int q = 0; q < 4; ++q) {
    const int wrd = slice * 4 + q;
    uint32_t wt[8];
#pragma unroll
    for (int t = 0; t < 8; ++t)
      wt[t] = spkbits2[((size_t)(t * 32 + wrd)) * 16384 + b];
    const float* wop = Wo + (size_t)a * 1024 + wrd * 32;
#pragma unroll
    for (int k8 = 0; k8 < 8; ++k8) {
      const float4 wv = *(const float4*)(wop + k8 * 4);
      const float wa[4] = {wv.x, wv.y, wv.z, wv.w};
#pragma unroll
      for (int kk = 0; kk < 4; ++kk) {
        const int k = k8 * 4 + kk;
#pragma unroll
        for (int t = 0; t < 8; ++t)
          s[t] += ((wt[t] >> k) & 1u) ? wa[kk] : 0.0f;
      }
    }
  }
  // reduce across slices (lanes stride-8 apart)
#pragma unroll
  for (int t = 0; t < 8; ++t) {
    s[t] += __shfl_down(s[t], 8, 64);
    s[t] += __shfl_down(s[t], 16, 64);
    s[t] += __shfl_down(s[t], 32, 64);
  }
  if (lane < 8) {
    const float bov = bo[a];
    float mo = 0.f, mx = -1e30f;
#pragma unroll
    for (int t = 0; t < 8; ++t) {
      mo = beo * mo + (s[t] + bov);
      mx = fmaxf(mx, mo);
    }
    out[(size_t)b * 8 + a] = mx;
  }
}

__global__ void zero_hdr_kernel(uint32_t* p) {
  if (threadIdx.x < 64) p[threadIdx.x] = 0;
}

__global__ void fill_sentinel(float* out, int n, float v) {
  int i = blockIdx.x * 256 + threadIdx.x;
  if (i < n) out[i] = v;
}

// ---------------- launch ----------------

extern "C" void kernel_launch(void* const* d_in, const int* in_sizes, int n_in,
                              void* d_out, int out_size, void* d_ws, size_t ws_size,
                              hipStream_t stream)
{
  (void)in_sizes; (void)n_in;
  const float* x   = (const float*)d_in[0];
  const float* W1  = (const float*)d_in[1];
  const float* b1  = (const float*)d_in[2];
  const float* W2  = (const float*)d_in[3];
  const float* b2  = (const float*)d_in[4];
  const float* Wo  = (const float*)d_in[5];
  const float* bo  = (const float*)d_in[6];
  const float* be1 = (const float*)d_in[7];
  const float* be2 = (const float*)d_in[8];
  const float* beo = (const float*)d_in[9];
  float* out = (float*)d_out;

  const int B = 16384, D = 512, H = 2048, H2 = 1024;

  const size_t sz_hdr  = 256;
  const size_t sz_Ax   = (size_t)B * 1024 * 2;        // 32 MB
  const size_t sz_W1s  = (size_t)H * 1024 * 2;        // 4 MB each
  const size_t sz_W2s  = (size_t)H2 * H * 2;          // 4 MB each
  const size_t sz_b1   = (size_t)8 * 64 * B * 4;      // 32 MB
  const size_t sz_b2   = (size_t)8 * 32 * B * 4;      // 16 MB
  const size_t sz_f1   = (size_t)CAP1 * 8;            // 16 MB
  const size_t sz_f2   = (size_t)CAP2 * 4;            // 8 MB
  const size_t need = sz_hdr + sz_Ax + 2 * sz_W1s + 2 * sz_W2s +
                      sz_b1 + sz_b2 + sz_f1 + sz_f2;  // ~120 MB

  if (ws_size < need) {
    fill_sentinel<<<(out_size + 255) / 256, 256, 0, stream>>>(
        out, out_size, 1000.0f + (float)(ws_size >> 20));
    return;
  }

  uint8_t* p = (uint8_t*)d_ws;
  uint32_t* hdr = (uint32_t*)p;     p += sz_hdr;
  bf16* Ax      = (bf16*)p;         p += sz_Ax;
  bf16* W1B0    = (bf16*)p;         p += sz_W1s;
  bf16* W1B1    = (bf16*)p;         p += sz_W1s;
  bf16* W2h     = (bf16*)p;         p += sz_W2s;
  bf16* W2l     = (bf16*)p;         p += sz_W2s;
  uint32_t* spkbits1 = (uint32_t*)p; p += sz_b1;
  uint32_t* spkbits2 = (uint32_t*)p; p += sz_b2;
  uint2* flag1  = (uint2*)p;        p += sz_f1;
  uint32_t* flag2 = (uint32_t*)p;   p += sz_f2;
  uint32_t* cnt1 = hdr + 0;
  uint32_t* cnt2 = hdr + 1;

  zero_hdr_kernel<<<1, 64, 0, stream>>>(hdr);
  split_x_kernel <<<(B * D) / 256, 256, 0, stream>>>(x, Ax);
  split_w1_kernel<<<(H * D) / 256, 256, 0, stream>>>(W1, W1B0, W1B1);
  split_w2_kernel<<<(H2 * H) / 256, 256, 0, stream>>>(W2, W2h, W2l);

  gemm1_lif1_kernel<<<dim3(B / 128, H / 128), 256, 0, stream>>>(
      Ax, W1B0, W1B1, b1, be1, spkbits1, flag1, cnt1);
  repair1_kernel<<<256, 256, 0, stream>>>(x, W1, b1, be1, flag1, cnt1, spkbits1);

  step2_kernel<<<dim3(B / 128, H2 / 128), 256, 0, stream>>>(
      spkbits1, W2h, W2l, b2, be2, spkbits2, flag2, cnt2);
  repair2_kernel<<<256, 256, 0, stream>>>(spkbits1, W2, b2, be2, flag2, cnt2, spkbits2);

  out_kernel<<<B / 4, 256, 0, stream>>>(spkbits2, Wo, bo, beo, out);
}